// Round 1
// baseline (1145.109 us; speedup 1.0000x reference)
//
#include <hip/hip_runtime.h>
#include <hip/hip_bf16.h>
#include <cstdint>
#include <cstddef>

// ---------------------------------------------------------------------------
// ChildSumTreeLSTM, complete binary tree N=131071=2^17-1, dim 256.
// Round 5: round-4 GEMM structure unchanged (GLD16 staging, XOR-swizzled LDS,
// m97-profile budgets). NEW: levels 10..0 (22 tiny dependent dispatches, <1%
// of FLOPs) fused into ONE persistent kernel with 64 co-resident blocks and a
// device-scope sense-reversal barrier -> removes ~22 launch/drain gaps.
//   iou: 128 rows x 32 ch (96 cols = 3 parts x 32), acc 48 AGPR, LDS 28 KB
//   f:   128 rows x 128 cols, acc 64 AGPR, LDS 32 KB
// ---------------------------------------------------------------------------

typedef __bf16 bf16;
typedef bf16 bf16x8 __attribute__((ext_vector_type(8)));
typedef float f32x4 __attribute__((ext_vector_type(4)));

#define LEAF_START 65535
#define LEAF_COUNT 65536
#define TAIL_TOP   10     // levels TAIL_TOP..0 run inside the persistent kernel
#define TAIL_GRID  64     // = iou tiles at lvl 10; trivially co-resident on 256 CUs

__device__ __forceinline__ float sigf(float x) { return 1.0f / (1.0f + __expf(-x)); }
__device__ __forceinline__ float tanh_fast(float x) {
  return 1.0f - 2.0f / (__expf(2.0f * x) + 1.0f);
}

// async global->LDS, 16 B per lane, dest = base + lane*16
#define GLD16(g, l) __builtin_amdgcn_global_load_lds(                         \
    (const __attribute__((address_space(1))) void*)(g),                       \
    (__attribute__((address_space(3))) void*)(l), 16, 0, 0)

__global__ void prep_weights(const float* __restrict__ Wioux, const float* __restrict__ Wiouh,
                             const float* __restrict__ Wfx, const float* __restrict__ Wfh,
                             const float* __restrict__ bioux, const float* __restrict__ biouh,
                             const float* __restrict__ bfx, const float* __restrict__ bfh,
                             bf16* __restrict__ Wiou, bf16* __restrict__ Wf,
                             float* __restrict__ biou, float* __restrict__ bfc,
                             unsigned* __restrict__ bar)
{
  const int el = blockIdx.x * 256 + threadIdx.x;   // 0 .. 524287
  if (el == 0) { bar[0] = 0u; bar[1] = 0u; }       // barrier state reset per replay
  if (el < 768 * 512) {
    const int r = el >> 9, c = el & 511;
    const float v = (c < 256) ? Wioux[r * 256 + c] : Wiouh[r * 256 + c - 256];
    Wiou[el] = (bf16)v;
  } else {
    const int e2 = el - 768 * 512;
    const int r = e2 >> 9, c = e2 & 511;
    const float v = (c < 256) ? Wfx[r * 256 + c] : Wfh[r * 256 + c - 256];
    Wf[e2] = (bf16)v;
  }
  if (el < 768)       biou[el] = bioux[el] + biouh[el];
  else if (el < 1024) bfc[el - 768] = bfx[el - 768] + bfh[el - 768];
}

__global__ void convert_x(const float* __restrict__ X, bf16* __restrict__ Xb)
{
  const int i = blockIdx.x * 256 + threadIdx.x;    // float4 index
  if (i < (131071 * 256) / 4) {
    const float4 v = ((const float4*)X)[i];
    union { ushort4 u; bf16 b[4]; } cv;
    cv.b[0] = (bf16)v.x; cv.b[1] = (bf16)v.y; cv.b[2] = (bf16)v.z; cv.b[3] = (bf16)v.w;
    ((ushort4*)Xb)[i] = cv.u;
  }
}

// IOU tile: A[M x K] = [ Xb[xbase+row] | Hsin[row] ], B = Wiou (768 x 512).
// Tile: 128 rows x 32 channels (96 cols: part*32+ch). Each wave: 64 rows
// (waveM) x 16 channels (waveN) x 3 parts -> lane-local i,o,u.
// Epilogue: c = sig(i)tanh(u) + FC; h = sig(o)tanh(c); emit C, H, Hsum.
__device__ __forceinline__ void iou_tile(
    bf16* __restrict__ As /*128*64*/, bf16* __restrict__ Bs /*96*64*/,
    const bf16* __restrict__ Xb, int xbase,
    const bf16* __restrict__ Hsin, const bf16* __restrict__ FCb,
    const float* __restrict__ biou, const bf16* __restrict__ Wiou,
    bf16* __restrict__ Cst, bf16* __restrict__ H, bf16* __restrict__ Hsout,
    float* __restrict__ out, int M, int K, int isRoot, int bx, int by)
{
  const int t = threadIdx.x;
  const int wave = t >> 6, lane = t & 63;
  const int quad = lane >> 4, lc = lane & 15;
  const int waveM = wave >> 1, waveN = wave & 1;
  const int mBase = by * 128;
  const int chBase = bx * 32;
  const int lrow = lane >> 3;                      // 0..7
  const int lcol8 = ((lane & 7) ^ lrow) << 3;      // swizzled 8-elem block
  const int Mm1 = M - 1;
  f32x4 acc[4][3] = {};

  auto ktile = [&](const bf16* __restrict__ abase, int ka, int kb) {
    // A: 16 issues (8 rows each); this wave does 4
#pragma unroll
    for (int ii = 0; ii < 4; ++ii) {
      const int idx = wave * 4 + ii;
      const int r = idx * 8 + lrow;
      int g = mBase + r; g = g > Mm1 ? Mm1 : g;
      GLD16(abase + (size_t)g * 256 + ka + lcol8, &As[idx * 512]);
    }
    // B: 12 issues; this wave does 3
#pragma unroll
    for (int ii = 0; ii < 3; ++ii) {
      const int idx = wave * 3 + ii;
      const int rb = idx * 8 + lrow;               // 0..95
      const int grow = (rb >> 5) * 256 + chBase + (rb & 31);
      GLD16(Wiou + (size_t)grow * 512 + kb + lcol8, &Bs[idx * 512]);
    }
    __syncthreads();
#pragma unroll
    for (int kk = 0; kk < 64; kk += 32) {
      const int lb = (kk >> 3) + quad;
      bf16x8 a[4];
#pragma unroll
      for (int mf = 0; mf < 4; ++mf) {
        const int rA = waveM * 64 + mf * 16 + lc;
        a[mf] = *(const bf16x8*)&As[rA * 64 + ((lb ^ (rA & 7)) << 3)];
      }
#pragma unroll
      for (int p = 0; p < 3; ++p) {
        const int rB = p * 32 + waveN * 16 + lc;
        bf16x8 b = *(const bf16x8*)&Bs[rB * 64 + ((lb ^ (rB & 7)) << 3)];
#pragma unroll
        for (int mf = 0; mf < 4; ++mf)
          acc[mf][p] = __builtin_amdgcn_mfma_f32_16x16x32_bf16(a[mf], b, acc[mf][p], 0, 0, 0);
      }
    }
    __syncthreads();
  };

#pragma unroll
  for (int kt = 0; kt < 256; kt += 64) ktile(Xb + (size_t)xbase * 256, kt, kt);
  if (K == 512) {
#pragma unroll
    for (int kt = 0; kt < 256; kt += 64) ktile(Hsin, kt, kt + 256);
  }

  const int ch = chBase + waveN * 16 + lc;
  const float bi = biou[ch], bo = biou[256 + ch], bu = biou[512 + ch];
#pragma unroll
  for (int mf = 0; mf < 4; ++mf) {
    const int row0 = mBase + waveM * 64 + mf * 16 + quad * 4;
    float hv[4] = {0.f, 0.f, 0.f, 0.f};
#pragma unroll
    for (int r = 0; r < 4; ++r) {
      const int rw = row0 + r;
      if (rw < M) {
        const float iv = acc[mf][0][r] + bi;
        const float ov = acc[mf][1][r] + bo;
        const float uv = acc[mf][2][r] + bu;
        const float fc = FCb ? (float)FCb[(size_t)rw * 256 + ch] : 0.0f;
        const float cv = sigf(iv) * tanh_fast(uv) + fc;
        const float h1 = sigf(ov) * tanh_fast(cv);
        hv[r] = h1;
        Cst[(size_t)rw * 256 + ch] = (bf16)cv;
        H[(size_t)rw * 256 + ch] = (bf16)h1;
        if (isRoot && rw == 0) { out[ch] = cv; out[256 + ch] = h1; }
      }
    }
    if (row0 + 1 < M) Hsout[(size_t)(row0 >> 1) * 256 + ch] = (bf16)(hv[0] + hv[1]);
    if (row0 + 3 < M) Hsout[(size_t)((row0 >> 1) + 1) * 256 + ch] = (bf16)(hv[2] + hv[3]);
  }
}

// F tile over children: A[j] = [ Xb[parent(j)] | H[j] ], B = Wf (256 x 512).
// m97 profile: 128 x 128 tile, waves 2x2, acc 64. Fused: FC = f0*c0 + f1*c1.
__device__ __forceinline__ void f_tile(
    bf16* __restrict__ As /*128*64*/, bf16* __restrict__ Bs /*128*64*/,
    const bf16* __restrict__ Xb, int xbase,
    const bf16* __restrict__ H, const bf16* __restrict__ Cc,
    const float* __restrict__ bfc, const bf16* __restrict__ Wf,
    bf16* __restrict__ FCb, int M2, int bx, int by)
{
  const int t = threadIdx.x;
  const int wave = t >> 6, lane = t & 63;
  const int quad = lane >> 4, lc = lane & 15;
  const int waveM = wave >> 1, waveN = wave & 1;
  const int mBase = by * 128;
  const int nBase = bx * 128;
  const int lrow = lane >> 3;
  const int lcol8 = ((lane & 7) ^ lrow) << 3;
  const int Mm1 = M2 - 1;
  f32x4 acc[4][4] = {};

  auto ktile = [&](bool xphase, int ka, int kb) {
#pragma unroll
    for (int ii = 0; ii < 4; ++ii) {
      const int idx = wave * 4 + ii;
      const int r = idx * 8 + lrow;
      int j = mBase + r; j = j > Mm1 ? Mm1 : j;
      const bf16* src = xphase ? Xb + (size_t)(xbase + (j >> 1)) * 256 + ka + lcol8
                               : H + (size_t)j * 256 + ka + lcol8;
      GLD16(src, &As[idx * 512]);
    }
#pragma unroll
    for (int ii = 0; ii < 4; ++ii) {
      const int idx = wave * 4 + ii;
      const int rb = idx * 8 + lrow;
      GLD16(Wf + (size_t)(nBase + rb) * 512 + kb + lcol8, &Bs[idx * 512]);
    }
    __syncthreads();
#pragma unroll
    for (int kk = 0; kk < 64; kk += 32) {
      const int lb = (kk >> 3) + quad;
      bf16x8 a[4];
#pragma unroll
      for (int mf = 0; mf < 4; ++mf) {
        const int rA = waveM * 64 + mf * 16 + lc;
        a[mf] = *(const bf16x8*)&As[rA * 64 + ((lb ^ (rA & 7)) << 3)];
      }
#pragma unroll
      for (int nf = 0; nf < 4; ++nf) {
        const int rB = waveN * 64 + nf * 16 + lc;
        bf16x8 b = *(const bf16x8*)&Bs[rB * 64 + ((lb ^ (rB & 7)) << 3)];
#pragma unroll
        for (int mf = 0; mf < 4; ++mf)
          acc[mf][nf] = __builtin_amdgcn_mfma_f32_16x16x32_bf16(a[mf], b, acc[mf][nf], 0, 0, 0);
      }
    }
    __syncthreads();
  };

#pragma unroll
  for (int kt = 0; kt < 256; kt += 64) ktile(true, kt, kt);
#pragma unroll
  for (int kt = 0; kt < 256; kt += 64) ktile(false, kt, kt + 256);

#pragma unroll
  for (int nf = 0; nf < 4; ++nf) {
    const int col = nBase + waveN * 64 + nf * 16 + lc;
    const float bv = bfc[col];
#pragma unroll
    for (int mf = 0; mf < 4; ++mf) {
      const int j0 = mBase + waveM * 64 + mf * 16 + quad * 4;
#pragma unroll
      for (int p = 0; p < 4; p += 2) {
        const int j = j0 + p;
        if (j < M2) {
          const float f0 = sigf(acc[mf][nf][p] + bv);
          const float f1 = sigf(acc[mf][nf][p + 1] + bv);
          const float c0 = (float)Cc[(size_t)j * 256 + col];
          const float c1 = (float)Cc[(size_t)(j + 1) * 256 + col];
          FCb[(size_t)(j >> 1) * 256 + col] = (bf16)(f0 * c0 + f1 * c1);
        }
      }
    }
  }
}

// Standalone wrappers for the large levels (grids as before).
__global__ __launch_bounds__(256) void iou_gemm(
    const bf16* __restrict__ Xb, int xbase,
    const bf16* __restrict__ Hsin, const bf16* __restrict__ FCb,
    const float* __restrict__ biou, const bf16* __restrict__ Wiou,
    bf16* __restrict__ Cst, bf16* __restrict__ H, bf16* __restrict__ Hsout,
    float* __restrict__ out, int M, int K, int isRoot)
{
  __shared__ bf16 As[128 * 64];   // 16 KB
  __shared__ bf16 Bs[96 * 64];    // 12 KB
  iou_tile(As, Bs, Xb, xbase, Hsin, FCb, biou, Wiou, Cst, H, Hsout, out,
           M, K, isRoot, blockIdx.x, blockIdx.y);
}

__global__ __launch_bounds__(256) void f_gemm(
    const bf16* __restrict__ Xb, int xbase,
    const bf16* __restrict__ H, const bf16* __restrict__ Cc,
    const float* __restrict__ bfc, const bf16* __restrict__ Wf,
    bf16* __restrict__ FCb, int M2)
{
  __shared__ bf16 As[128 * 64];
  __shared__ bf16 Bs[128 * 64];
  f_tile(As, Bs, Xb, xbase, H, Cc, bfc, Wf, FCb, M2, blockIdx.x, blockIdx.y);
}

// Device-scope sense-reversal barrier. bar[0]=arrival count (returns to 0),
// bar[1]=generation (monotone, compared only for change -> replay-safe).
// Per-XCD L2s are not cross-coherent: agent-scope fences on both sides.
__device__ __forceinline__ void gbar(unsigned* bar)
{
  __threadfence();            // release this thread's stores to device scope
  __syncthreads();            // all waves of the block have fenced
  if (threadIdx.x == 0) {
    const unsigned g = __hip_atomic_load(bar + 1, __ATOMIC_RELAXED, __HIP_MEMORY_SCOPE_AGENT);
    const unsigned G = gridDim.x;
    if (__hip_atomic_fetch_add(bar, 1u, __ATOMIC_ACQ_REL, __HIP_MEMORY_SCOPE_AGENT) == G - 1u) {
      __hip_atomic_store(bar, 0u, __ATOMIC_RELAXED, __HIP_MEMORY_SCOPE_AGENT);
      __hip_atomic_fetch_add(bar + 1, 1u, __ATOMIC_RELEASE, __HIP_MEMORY_SCOPE_AGENT);
    } else {
      while (__hip_atomic_load(bar + 1, __ATOMIC_ACQUIRE, __HIP_MEMORY_SCOPE_AGENT) == g)
        __builtin_amdgcn_s_sleep(4);
    }
  }
  __syncthreads();
  __threadfence();            // acquire: invalidate stale L1/L2 lines
}

// Persistent kernel for levels TAIL_TOP..0. Tile->block mapping reproduces the
// original per-level grids exactly; blocks with no tile just hit the barrier.
__global__ __launch_bounds__(256) void tail_levels(
    const bf16* __restrict__ Xb,
    bf16* __restrict__ H, bf16* __restrict__ C,
    bf16* __restrict__ HsA, bf16* __restrict__ HsB, bf16* __restrict__ FCb,
    const float* __restrict__ biou, const float* __restrict__ bfc,
    const bf16* __restrict__ Wiou, const bf16* __restrict__ Wf,
    float* __restrict__ out, unsigned* __restrict__ bar)
{
  __shared__ bf16 As[128 * 64];
  __shared__ bf16 Bs[128 * 64];
  const int G = gridDim.x;

  for (int lvl = TAIL_TOP; lvl >= 0; --lvl) {
    const int count = 1 << lvl;
    const int s = count - 1;
    const int M2 = count << 1;
    const bf16* Hsin = (lvl & 1) ? HsA : HsB;
    bf16* Hsout      = (lvl & 1) ? HsB : HsA;

    const int fTiles = 2 * ((M2 + 127) >> 7);          // grid (2, ceil(M2/128))
    for (int tt = blockIdx.x; tt < fTiles; tt += G)
      f_tile(As, Bs, Xb, s, H, C, bfc, Wf, FCb, M2, tt & 1, tt >> 1);
    gbar(bar);                                          // FCb visible

    const int iTiles = 8 * ((count + 127) >> 7);        // grid (8, ceil(count/128))
    for (int tt = blockIdx.x; tt < iTiles; tt += G)
      iou_tile(As, Bs, Xb, s, Hsin, FCb, biou, Wiou, C, H, Hsout, out,
               count, 512, lvl == 0, tt & 7, tt >> 3);
    gbar(bar);                                          // C/H/Hsout visible
  }
}

extern "C" void kernel_launch(void* const* d_in, const int* in_sizes, int n_in,
                              void* d_out, int out_size, void* d_ws, size_t ws_size,
                              hipStream_t stream)
{
  const float* X      = (const float*)d_in[0];
  const float* Wioux  = (const float*)d_in[1];
  const float* bioux  = (const float*)d_in[2];
  const float* Wiouh  = (const float*)d_in[3];
  const float* biouh  = (const float*)d_in[4];
  const float* Wfx    = (const float*)d_in[5];
  const float* bfx    = (const float*)d_in[6];
  const float* Wfh    = (const float*)d_in[7];
  const float* bfh    = (const float*)d_in[8];
  float* out = (float*)d_out;
  (void)in_sizes; (void)n_in; (void)out_size; (void)ws_size;

  // workspace: ~185.6 MB (proven footprint) + 256 B barrier state
  char* ws = (char*)d_ws;
  size_t off = 0;
  auto alloc = [&](size_t bytes) -> char* {
    char* p = ws + off;
    off += (bytes + 255) & ~(size_t)255;
    return p;
  };
  bf16*  Wiou = (bf16*)alloc((size_t)768 * 512 * 2);
  bf16*  Wf   = (bf16*)alloc((size_t)256 * 512 * 2);
  float* biou = (float*)alloc(768 * 4);
  float* bfc  = (float*)alloc(256 * 4);
  bf16*  Xb   = (bf16*)alloc((size_t)131071 * 256 * 2);  // 67.1 MB
  bf16*  H    = (bf16*)alloc((size_t)65536 * 256 * 2);   // 33.6 MB (level-local)
  bf16*  HsA  = (bf16*)alloc((size_t)32768 * 256 * 2);   // 16.8 MB
  bf16*  HsB  = (bf16*)alloc((size_t)32768 * 256 * 2);   // 16.8 MB
  bf16*  FCb  = (bf16*)alloc((size_t)32768 * 256 * 2);   // 16.8 MB
  bf16*  C    = (bf16*)alloc((size_t)65536 * 256 * 2);   // 33.6 MB (level-local)
  unsigned* bar = (unsigned*)alloc(256);

  prep_weights<<<2048, 256, 0, stream>>>(Wioux, Wiouh, Wfx, Wfh,
                                         bioux, biouh, bfx, bfh,
                                         Wiou, Wf, biou, bfc, bar);
  convert_x<<<32768, 256, 0, stream>>>(X, Xb);

  // Leaf level: K=256 (x only); writes C/H rows [0,65536), HsA [0,32768)
  iou_gemm<<<dim3(8, 512), 256, 0, stream>>>(
      Xb, LEAF_START, HsA /*unused*/, nullptr, biou, Wiou,
      C, H, HsA, out, LEAF_COUNT, 256, 0);

  // Large internal levels, bottom-up (separate dispatches keep full grids).
  for (int lvl = 15; lvl > TAIL_TOP; --lvl) {
    const int count = 1 << lvl;
    const int s = count - 1;
    const int M2 = 2 * count;
    const bf16* Hsin = (lvl & 1) ? HsA : HsB;
    bf16* Hsout      = (lvl & 1) ? HsB : HsA;
    f_gemm<<<dim3(2, (M2 + 127) / 128), 256, 0, stream>>>(
        Xb, s, H, C, bfc, Wf, FCb, M2);
    iou_gemm<<<dim3(8, (count + 127) / 128), 256, 0, stream>>>(
        Xb, s, Hsin, FCb, biou, Wiou, C, H, Hsout, out, count, 512, 0);
  }

  // Levels TAIL_TOP..0: one persistent kernel, global barriers between phases.
  tail_levels<<<dim3(TAIL_GRID), 256, 0, stream>>>(
      Xb, H, C, HsA, HsB, FCb, biou, bfc, Wiou, Wf, out, bar);
}

// Round 2
// 988.214 us; speedup vs baseline: 1.1588x; 1.1588x over previous
//
#include <hip/hip_runtime.h>
#include <hip/hip_bf16.h>
#include <cstdint>
#include <cstddef>

// ---------------------------------------------------------------------------
// ChildSumTreeLSTM, complete binary tree N=131071=2^17-1, dim 256.
// Round 6: r5 structure (levels 10..0 in one persistent kernel) with the
// global barrier REWRITTEN flag-based. r5 post-mortem: 64 same-line agent-scope
// acq_rel RMWs serialize at ~400ns each = ~26us/barrier (x22 = 550us of the
// 583us tail). New barrier: per-block flag lines (parallel release stores),
// block-0 poller with one lane per flag, RELAXED polls (no per-poll
// invalidates), single generation broadcast. Expected ~2-3us/barrier.
//   iou: 128 rows x 32 ch (96 cols = 3 parts x 32), acc 48 AGPR, LDS 28 KB
//   f:   128 rows x 128 cols, acc 64 AGPR, LDS 32 KB
// ---------------------------------------------------------------------------

typedef __bf16 bf16;
typedef bf16 bf16x8 __attribute__((ext_vector_type(8)));
typedef float f32x4 __attribute__((ext_vector_type(4)));

#define LEAF_START 65535
#define LEAF_COUNT 65536
#define TAIL_TOP   10     // levels TAIL_TOP..0 run inside the persistent kernel
#define TAIL_GRID  64     // = iou tiles at lvl 10; trivially co-resident on 256 CUs

__device__ __forceinline__ float sigf(float x) { return 1.0f / (1.0f + __expf(-x)); }
__device__ __forceinline__ float tanh_fast(float x) {
  return 1.0f - 2.0f / (__expf(2.0f * x) + 1.0f);
}

// async global->LDS, 16 B per lane, dest = base + lane*16
#define GLD16(g, l) __builtin_amdgcn_global_load_lds(                         \
    (const __attribute__((address_space(1))) void*)(g),                       \
    (__attribute__((address_space(3))) void*)(l), 16, 0, 0)

__global__ void prep_weights(const float* __restrict__ Wioux, const float* __restrict__ Wiouh,
                             const float* __restrict__ Wfx, const float* __restrict__ Wfh,
                             const float* __restrict__ bioux, const float* __restrict__ biouh,
                             const float* __restrict__ bfx, const float* __restrict__ bfh,
                             bf16* __restrict__ Wiou, bf16* __restrict__ Wf,
                             float* __restrict__ biou, float* __restrict__ bfc,
                             unsigned* __restrict__ bar)
{
  const int el = blockIdx.x * 256 + threadIdx.x;   // 0 .. 524287
  if (el < 2048) bar[el] = 0u;                     // barrier state reset per replay
  if (el < 768 * 512) {
    const int r = el >> 9, c = el & 511;
    const float v = (c < 256) ? Wioux[r * 256 + c] : Wiouh[r * 256 + c - 256];
    Wiou[el] = (bf16)v;
  } else {
    const int e2 = el - 768 * 512;
    const int r = e2 >> 9, c = e2 & 511;
    const float v = (c < 256) ? Wfx[r * 256 + c] : Wfh[r * 256 + c - 256];
    Wf[e2] = (bf16)v;
  }
  if (el < 768)       biou[el] = bioux[el] + biouh[el];
  else if (el < 1024) bfc[el - 768] = bfx[el - 768] + bfh[el - 768];
}

__global__ void convert_x(const float* __restrict__ X, bf16* __restrict__ Xb)
{
  const int i = blockIdx.x * 256 + threadIdx.x;    // float4 index
  if (i < (131071 * 256) / 4) {
    const float4 v = ((const float4*)X)[i];
    union { ushort4 u; bf16 b[4]; } cv;
    cv.b[0] = (bf16)v.x; cv.b[1] = (bf16)v.y; cv.b[2] = (bf16)v.z; cv.b[3] = (bf16)v.w;
    ((ushort4*)Xb)[i] = cv.u;
  }
}

// IOU tile: A[M x K] = [ Xb[xbase+row] | Hsin[row] ], B = Wiou (768 x 512).
// Tile: 128 rows x 32 channels (96 cols: part*32+ch). Each wave: 64 rows
// (waveM) x 16 channels (waveN) x 3 parts -> lane-local i,o,u.
// Epilogue: c = sig(i)tanh(u) + FC; h = sig(o)tanh(c); emit C, H, Hsum.
__device__ __forceinline__ void iou_tile(
    bf16* __restrict__ As /*128*64*/, bf16* __restrict__ Bs /*96*64*/,
    const bf16* __restrict__ Xb, int xbase,
    const bf16* __restrict__ Hsin, const bf16* __restrict__ FCb,
    const float* __restrict__ biou, const bf16* __restrict__ Wiou,
    bf16* __restrict__ Cst, bf16* __restrict__ H, bf16* __restrict__ Hsout,
    float* __restrict__ out, int M, int K, int isRoot, int bx, int by)
{
  const int t = threadIdx.x;
  const int wave = t >> 6, lane = t & 63;
  const int quad = lane >> 4, lc = lane & 15;
  const int waveM = wave >> 1, waveN = wave & 1;
  const int mBase = by * 128;
  const int chBase = bx * 32;
  const int lrow = lane >> 3;                      // 0..7
  const int lcol8 = ((lane & 7) ^ lrow) << 3;      // swizzled 8-elem block
  const int Mm1 = M - 1;
  f32x4 acc[4][3] = {};

  auto ktile = [&](const bf16* __restrict__ abase, int ka, int kb) {
    // A: 16 issues (8 rows each); this wave does 4
#pragma unroll
    for (int ii = 0; ii < 4; ++ii) {
      const int idx = wave * 4 + ii;
      const int r = idx * 8 + lrow;
      int g = mBase + r; g = g > Mm1 ? Mm1 : g;
      GLD16(abase + (size_t)g * 256 + ka + lcol8, &As[idx * 512]);
    }
    // B: 12 issues; this wave does 3
#pragma unroll
    for (int ii = 0; ii < 3; ++ii) {
      const int idx = wave * 3 + ii;
      const int rb = idx * 8 + lrow;               // 0..95
      const int grow = (rb >> 5) * 256 + chBase + (rb & 31);
      GLD16(Wiou + (size_t)grow * 512 + kb + lcol8, &Bs[idx * 512]);
    }
    __syncthreads();
#pragma unroll
    for (int kk = 0; kk < 64; kk += 32) {
      const int lb = (kk >> 3) + quad;
      bf16x8 a[4];
#pragma unroll
      for (int mf = 0; mf < 4; ++mf) {
        const int rA = waveM * 64 + mf * 16 + lc;
        a[mf] = *(const bf16x8*)&As[rA * 64 + ((lb ^ (rA & 7)) << 3)];
      }
#pragma unroll
      for (int p = 0; p < 3; ++p) {
        const int rB = p * 32 + waveN * 16 + lc;
        bf16x8 b = *(const bf16x8*)&Bs[rB * 64 + ((lb ^ (rB & 7)) << 3)];
#pragma unroll
        for (int mf = 0; mf < 4; ++mf)
          acc[mf][p] = __builtin_amdgcn_mfma_f32_16x16x32_bf16(a[mf], b, acc[mf][p], 0, 0, 0);
      }
    }
    __syncthreads();
  };

#pragma unroll
  for (int kt = 0; kt < 256; kt += 64) ktile(Xb + (size_t)xbase * 256, kt, kt);
  if (K == 512) {
#pragma unroll
    for (int kt = 0; kt < 256; kt += 64) ktile(Hsin, kt, kt + 256);
  }

  const int ch = chBase + waveN * 16 + lc;
  const float bi = biou[ch], bo = biou[256 + ch], bu = biou[512 + ch];
#pragma unroll
  for (int mf = 0; mf < 4; ++mf) {
    const int row0 = mBase + waveM * 64 + mf * 16 + quad * 4;
    float hv[4] = {0.f, 0.f, 0.f, 0.f};
#pragma unroll
    for (int r = 0; r < 4; ++r) {
      const int rw = row0 + r;
      if (rw < M) {
        const float iv = acc[mf][0][r] + bi;
        const float ov = acc[mf][1][r] + bo;
        const float uv = acc[mf][2][r] + bu;
        const float fc = FCb ? (float)FCb[(size_t)rw * 256 + ch] : 0.0f;
        const float cv = sigf(iv) * tanh_fast(uv) + fc;
        const float h1 = sigf(ov) * tanh_fast(cv);
        hv[r] = h1;
        Cst[(size_t)rw * 256 + ch] = (bf16)cv;
        H[(size_t)rw * 256 + ch] = (bf16)h1;
        if (isRoot && rw == 0) { out[ch] = cv; out[256 + ch] = h1; }
      }
    }
    if (row0 + 1 < M) Hsout[(size_t)(row0 >> 1) * 256 + ch] = (bf16)(hv[0] + hv[1]);
    if (row0 + 3 < M) Hsout[(size_t)((row0 >> 1) + 1) * 256 + ch] = (bf16)(hv[2] + hv[3]);
  }
}

// F tile over children: A[j] = [ Xb[parent(j)] | H[j] ], B = Wf (256 x 512).
// m97 profile: 128 x 128 tile, waves 2x2, acc 64. Fused: FC = f0*c0 + f1*c1.
__device__ __forceinline__ void f_tile(
    bf16* __restrict__ As /*128*64*/, bf16* __restrict__ Bs /*128*64*/,
    const bf16* __restrict__ Xb, int xbase,
    const bf16* __restrict__ H, const bf16* __restrict__ Cc,
    const float* __restrict__ bfc, const bf16* __restrict__ Wf,
    bf16* __restrict__ FCb, int M2, int bx, int by)
{
  const int t = threadIdx.x;
  const int wave = t >> 6, lane = t & 63;
  const int quad = lane >> 4, lc = lane & 15;
  const int waveM = wave >> 1, waveN = wave & 1;
  const int mBase = by * 128;
  const int nBase = bx * 128;
  const int lrow = lane >> 3;
  const int lcol8 = ((lane & 7) ^ lrow) << 3;
  const int Mm1 = M2 - 1;
  f32x4 acc[4][4] = {};

  auto ktile = [&](bool xphase, int ka, int kb) {
#pragma unroll
    for (int ii = 0; ii < 4; ++ii) {
      const int idx = wave * 4 + ii;
      const int r = idx * 8 + lrow;
      int j = mBase + r; j = j > Mm1 ? Mm1 : j;
      const bf16* src = xphase ? Xb + (size_t)(xbase + (j >> 1)) * 256 + ka + lcol8
                               : H + (size_t)j * 256 + ka + lcol8;
      GLD16(src, &As[idx * 512]);
    }
#pragma unroll
    for (int ii = 0; ii < 4; ++ii) {
      const int idx = wave * 4 + ii;
      const int rb = idx * 8 + lrow;
      GLD16(Wf + (size_t)(nBase + rb) * 512 + kb + lcol8, &Bs[idx * 512]);
    }
    __syncthreads();
#pragma unroll
    for (int kk = 0; kk < 64; kk += 32) {
      const int lb = (kk >> 3) + quad;
      bf16x8 a[4];
#pragma unroll
      for (int mf = 0; mf < 4; ++mf) {
        const int rA = waveM * 64 + mf * 16 + lc;
        a[mf] = *(const bf16x8*)&As[rA * 64 + ((lb ^ (rA & 7)) << 3)];
      }
#pragma unroll
      for (int nf = 0; nf < 4; ++nf) {
        const int rB = waveN * 64 + nf * 16 + lc;
        bf16x8 b = *(const bf16x8*)&Bs[rB * 64 + ((lb ^ (rB & 7)) << 3)];
#pragma unroll
        for (int mf = 0; mf < 4; ++mf)
          acc[mf][nf] = __builtin_amdgcn_mfma_f32_16x16x32_bf16(a[mf], b, acc[mf][nf], 0, 0, 0);
      }
    }
    __syncthreads();
  };

#pragma unroll
  for (int kt = 0; kt < 256; kt += 64) ktile(true, kt, kt);
#pragma unroll
  for (int kt = 0; kt < 256; kt += 64) ktile(false, kt, kt + 256);

#pragma unroll
  for (int nf = 0; nf < 4; ++nf) {
    const int col = nBase + waveN * 64 + nf * 16 + lc;
    const float bv = bfc[col];
#pragma unroll
    for (int mf = 0; mf < 4; ++mf) {
      const int j0 = mBase + waveM * 64 + mf * 16 + quad * 4;
#pragma unroll
      for (int p = 0; p < 4; p += 2) {
        const int j = j0 + p;
        if (j < M2) {
          const float f0 = sigf(acc[mf][nf][p] + bv);
          const float f1 = sigf(acc[mf][nf][p + 1] + bv);
          const float c0 = (float)Cc[(size_t)j * 256 + col];
          const float c1 = (float)Cc[(size_t)(j + 1) * 256 + col];
          FCb[(size_t)(j >> 1) * 256 + col] = (bf16)(f0 * c0 + f1 * c1);
        }
      }
    }
  }
}

// Standalone wrappers for the large levels (grids as before).
__global__ __launch_bounds__(256) void iou_gemm(
    const bf16* __restrict__ Xb, int xbase,
    const bf16* __restrict__ Hsin, const bf16* __restrict__ FCb,
    const float* __restrict__ biou, const bf16* __restrict__ Wiou,
    bf16* __restrict__ Cst, bf16* __restrict__ H, bf16* __restrict__ Hsout,
    float* __restrict__ out, int M, int K, int isRoot)
{
  __shared__ bf16 As[128 * 64];   // 16 KB
  __shared__ bf16 Bs[96 * 64];    // 12 KB
  iou_tile(As, Bs, Xb, xbase, Hsin, FCb, biou, Wiou, Cst, H, Hsout, out,
           M, K, isRoot, blockIdx.x, blockIdx.y);
}

__global__ __launch_bounds__(256) void f_gemm(
    const bf16* __restrict__ Xb, int xbase,
    const bf16* __restrict__ H, const bf16* __restrict__ Cc,
    const float* __restrict__ bfc, const bf16* __restrict__ Wf,
    bf16* __restrict__ FCb, int M2)
{
  __shared__ bf16 As[128 * 64];
  __shared__ bf16 Bs[128 * 64];
  f_tile(As, Bs, Xb, xbase, H, Cc, bfc, Wf, FCb, M2, blockIdx.x, blockIdx.y);
}

// Flag-based device-scope barrier (r5 post-mortem: same-line acq_rel RMWs from
// 64 blocks serialize -> ~26us/barrier; this replaces them).
// Layout: bar[0..1023] = per-block flags, one 64B line each (stride 16 u32);
//         bar[1024]    = generation broadcast (own line).
// g = generation value for THIS barrier instance (1,2,3,... within a launch;
// zeroed by prep_weights each replay -> replay-safe).
// RELAXED agent-scope polls still read the coherence point (no per-poll
// invalidate storm); one __threadfence() after exit = acquire side.
__device__ __forceinline__ void gbar(unsigned* __restrict__ bar, unsigned g)
{
  __threadfence();            // release: each thread's stores drained to device scope
  __syncthreads();
  const unsigned b = blockIdx.x;
  if (b == 0) {
    const int o = threadIdx.x;            // lane o polls block o's flag
    if (o > 0 && o < (int)gridDim.x) {
      while (__hip_atomic_load(&bar[o * 16], __ATOMIC_RELAXED, __HIP_MEMORY_SCOPE_AGENT) < g)
        __builtin_amdgcn_s_sleep(1);
    }
    __syncthreads();                      // all arrivals observed
    if (threadIdx.x == 0)
      __hip_atomic_store(&bar[1024], g, __ATOMIC_RELEASE, __HIP_MEMORY_SCOPE_AGENT);
  } else if (threadIdx.x == 0) {
    __hip_atomic_store(&bar[b * 16], g, __ATOMIC_RELEASE, __HIP_MEMORY_SCOPE_AGENT);
    while (__hip_atomic_load(&bar[1024], __ATOMIC_RELAXED, __HIP_MEMORY_SCOPE_AGENT) < g)
      __builtin_amdgcn_s_sleep(1);
  }
  __syncthreads();
  __threadfence();            // acquire: invalidate stale cached lines before reads
}

// Persistent kernel for levels TAIL_TOP..0. Tile->block mapping reproduces the
// original per-level grids exactly; blocks with no tile just hit the barrier.
__global__ __launch_bounds__(256) void tail_levels(
    const bf16* __restrict__ Xb,
    bf16* __restrict__ H, bf16* __restrict__ C,
    bf16* __restrict__ HsA, bf16* __restrict__ HsB, bf16* __restrict__ FCb,
    const float* __restrict__ biou, const float* __restrict__ bfc,
    const bf16* __restrict__ Wiou, const bf16* __restrict__ Wf,
    float* __restrict__ out, unsigned* __restrict__ bar)
{
  __shared__ bf16 As[128 * 64];
  __shared__ bf16 Bs[128 * 64];
  const int G = gridDim.x;
  unsigned gen = 0;

  for (int lvl = TAIL_TOP; lvl >= 0; --lvl) {
    const int count = 1 << lvl;
    const int s = count - 1;
    const int M2 = count << 1;
    const bf16* Hsin = (lvl & 1) ? HsA : HsB;
    bf16* Hsout      = (lvl & 1) ? HsB : HsA;

    const int fTiles = 2 * ((M2 + 127) >> 7);          // grid (2, ceil(M2/128))
    for (int tt = blockIdx.x; tt < fTiles; tt += G)
      f_tile(As, Bs, Xb, s, H, C, bfc, Wf, FCb, M2, tt & 1, tt >> 1);
    gbar(bar, ++gen);                                   // FCb visible

    const int iTiles = 8 * ((count + 127) >> 7);        // grid (8, ceil(count/128))
    for (int tt = blockIdx.x; tt < iTiles; tt += G)
      iou_tile(As, Bs, Xb, s, Hsin, FCb, biou, Wiou, C, H, Hsout, out,
               count, 512, lvl == 0, tt & 7, tt >> 3);
    gbar(bar, ++gen);                                   // C/H/Hsout visible
  }
}

extern "C" void kernel_launch(void* const* d_in, const int* in_sizes, int n_in,
                              void* d_out, int out_size, void* d_ws, size_t ws_size,
                              hipStream_t stream)
{
  const float* X      = (const float*)d_in[0];
  const float* Wioux  = (const float*)d_in[1];
  const float* bioux  = (const float*)d_in[2];
  const float* Wiouh  = (const float*)d_in[3];
  const float* biouh  = (const float*)d_in[4];
  const float* Wfx    = (const float*)d_in[5];
  const float* bfx    = (const float*)d_in[6];
  const float* Wfh    = (const float*)d_in[7];
  const float* bfh    = (const float*)d_in[8];
  float* out = (float*)d_out;
  (void)in_sizes; (void)n_in; (void)out_size; (void)ws_size;

  // workspace: ~185.6 MB (proven footprint) + 8 KB barrier state
  char* ws = (char*)d_ws;
  size_t off = 0;
  auto alloc = [&](size_t bytes) -> char* {
    char* p = ws + off;
    off += (bytes + 255) & ~(size_t)255;
    return p;
  };
  bf16*  Wiou = (bf16*)alloc((size_t)768 * 512 * 2);
  bf16*  Wf   = (bf16*)alloc((size_t)256 * 512 * 2);
  float* biou = (float*)alloc(768 * 4);
  float* bfc  = (float*)alloc(256 * 4);
  bf16*  Xb   = (bf16*)alloc((size_t)131071 * 256 * 2);  // 67.1 MB
  bf16*  H    = (bf16*)alloc((size_t)65536 * 256 * 2);   // 33.6 MB (level-local)
  bf16*  HsA  = (bf16*)alloc((size_t)32768 * 256 * 2);   // 16.8 MB
  bf16*  HsB  = (bf16*)alloc((size_t)32768 * 256 * 2);   // 16.8 MB
  bf16*  FCb  = (bf16*)alloc((size_t)32768 * 256 * 2);   // 16.8 MB
  bf16*  C    = (bf16*)alloc((size_t)65536 * 256 * 2);   // 33.6 MB (level-local)
  unsigned* bar = (unsigned*)alloc(8192);                // 1025 u32 used

  prep_weights<<<2048, 256, 0, stream>>>(Wioux, Wiouh, Wfx, Wfh,
                                         bioux, biouh, bfx, bfh,
                                         Wiou, Wf, biou, bfc, bar);
  convert_x<<<32768, 256, 0, stream>>>(X, Xb);

  // Leaf level: K=256 (x only); writes C/H rows [0,65536), HsA [0,32768)
  iou_gemm<<<dim3(8, 512), 256, 0, stream>>>(
      Xb, LEAF_START, HsA /*unused*/, nullptr, biou, Wiou,
      C, H, HsA, out, LEAF_COUNT, 256, 0);

  // Large internal levels, bottom-up (separate dispatches keep full grids).
  for (int lvl = 15; lvl > TAIL_TOP; --lvl) {
    const int count = 1 << lvl;
    const int s = count - 1;
    const int M2 = 2 * count;
    const bf16* Hsin = (lvl & 1) ? HsA : HsB;
    bf16* Hsout      = (lvl & 1) ? HsB : HsA;
    f_gemm<<<dim3(2, (M2 + 127) / 128), 256, 0, stream>>>(
        Xb, s, H, C, bfc, Wf, FCb, M2);
    iou_gemm<<<dim3(8, (count + 127) / 128), 256, 0, stream>>>(
        Xb, s, Hsin, FCb, biou, Wiou, C, H, Hsout, out, count, 512, 0);
  }

  // Levels TAIL_TOP..0: one persistent kernel, global barriers between phases.
  tail_levels<<<dim3(TAIL_GRID), 256, 0, stream>>>(
      Xb, H, C, HsA, HsB, FCb, biou, bfc, Wiou, Wf, out, bar);
}

// Round 3
// 773.487 us; speedup vs baseline: 1.4805x; 1.2776x over previous
//
#include <hip/hip_runtime.h>
#include <hip/hip_bf16.h>
#include <cstdint>
#include <cstddef>

// ---------------------------------------------------------------------------
// ChildSumTreeLSTM, complete binary tree N=131071=2^17-1, dim 256.
// Round 7: persistent kernel + global barrier DELETED (r6 post-mortem: ~15us
// residual/barrier ~= device-scope fence cost: buffer_wbl2/buffer_inv walk the
// whole 4MiB XCD L2, x2 per barrier, + post-invalidate cold refetch).
// Instead: levels 10..0 run as 11 dispatches of ONE fused kernel that computes
// the f-GEMM for its own 32 output channels (256 child rows x 32 cols -> zero
// redundant FLOPs across blocks), keeps FC in LDS (16KB, never global), then
// runs the iou tile after a plain __syncthreads. Cross-block WAR on H/C fixed
// by ping-ponging into small H2/C2 (1MB) buffers in the fused region.
// Levels 15..11 + leaf keep the proven f_gemm/iou_gemm two-dispatch scheme.
//   iou tile: 128 rows x 32 ch (96 cols = 3 parts x 32), acc 48 VGPR
//   f part:   256 child rows x 32 cols, acc 32 VGPR
//   fused LDS: 32+4+16+16+12 = 80 KB static
// ---------------------------------------------------------------------------

typedef __bf16 bf16;
typedef bf16 bf16x8 __attribute__((ext_vector_type(8)));
typedef float f32x4 __attribute__((ext_vector_type(4)));

#define LEAF_START 65535
#define LEAF_COUNT 65536
#define FUSE_TOP   10     // levels FUSE_TOP..0 use the fused one-dispatch-per-level kernel

__device__ __forceinline__ float sigf(float x) { return 1.0f / (1.0f + __expf(-x)); }
__device__ __forceinline__ float tanh_fast(float x) {
  return 1.0f - 2.0f / (__expf(2.0f * x) + 1.0f);
}

// async global->LDS, 16 B per lane, dest = base + lane*16
#define GLD16(g, l) __builtin_amdgcn_global_load_lds(                         \
    (const __attribute__((address_space(1))) void*)(g),                       \
    (__attribute__((address_space(3))) void*)(l), 16, 0, 0)

__global__ void prep_weights(const float* __restrict__ Wioux, const float* __restrict__ Wiouh,
                             const float* __restrict__ Wfx, const float* __restrict__ Wfh,
                             const float* __restrict__ bioux, const float* __restrict__ biouh,
                             const float* __restrict__ bfx, const float* __restrict__ bfh,
                             bf16* __restrict__ Wiou, bf16* __restrict__ Wf,
                             float* __restrict__ biou, float* __restrict__ bfc)
{
  const int el = blockIdx.x * 256 + threadIdx.x;   // 0 .. 524287
  if (el < 768 * 512) {
    const int r = el >> 9, c = el & 511;
    const float v = (c < 256) ? Wioux[r * 256 + c] : Wiouh[r * 256 + c - 256];
    Wiou[el] = (bf16)v;
  } else {
    const int e2 = el - 768 * 512;
    const int r = e2 >> 9, c = e2 & 511;
    const float v = (c < 256) ? Wfx[r * 256 + c] : Wfh[r * 256 + c - 256];
    Wf[e2] = (bf16)v;
  }
  if (el < 768)       biou[el] = bioux[el] + biouh[el];
  else if (el < 1024) bfc[el - 768] = bfx[el - 768] + bfh[el - 768];
}

__global__ void convert_x(const float* __restrict__ X, bf16* __restrict__ Xb)
{
  const int i = blockIdx.x * 256 + threadIdx.x;    // float4 index
  if (i < (131071 * 256) / 4) {
    const float4 v = ((const float4*)X)[i];
    union { ushort4 u; bf16 b[4]; } cv;
    cv.b[0] = (bf16)v.x; cv.b[1] = (bf16)v.y; cv.b[2] = (bf16)v.z; cv.b[3] = (bf16)v.w;
    ((ushort4*)Xb)[i] = cv.u;
  }
}

// IOU tile: A[M x K] = [ Xb[xbase+row] | Hsin[row] ], B = Wiou (768 x 512).
// Tile: 128 rows x 32 channels (96 cols: part*32+ch). Each wave: 64 rows
// (waveM) x 16 channels (waveN) x 3 parts -> lane-local i,o,u.
// FC source: FCs (LDS, fused path) > FCb (global) > none (leaf).
// Epilogue: c = sig(i)tanh(u) + FC; h = sig(o)tanh(c); emit C, H, Hsum.
__device__ __forceinline__ void iou_tile(
    bf16* __restrict__ As /*128*64*/, bf16* __restrict__ Bs /*96*64*/,
    const bf16* __restrict__ Xb, int xbase,
    const bf16* __restrict__ Hsin,
    const bf16* __restrict__ FCb, const float* FCs,
    const float* __restrict__ biou, const bf16* __restrict__ Wiou,
    bf16* __restrict__ Cst, bf16* __restrict__ H, bf16* __restrict__ Hsout,
    float* __restrict__ out, int M, int K, int isRoot, int bx, int by)
{
  const int t = threadIdx.x;
  const int wave = t >> 6, lane = t & 63;
  const int quad = lane >> 4, lc = lane & 15;
  const int waveM = wave >> 1, waveN = wave & 1;
  const int mBase = by * 128;
  const int chBase = bx * 32;
  const int lrow = lane >> 3;                      // 0..7
  const int lcol8 = ((lane & 7) ^ lrow) << 3;      // swizzled 8-elem block
  const int Mm1 = M - 1;
  f32x4 acc[4][3] = {};

  auto ktile = [&](const bf16* __restrict__ abase, int ka, int kb) {
    // A: 16 issues (8 rows each); this wave does 4
#pragma unroll
    for (int ii = 0; ii < 4; ++ii) {
      const int idx = wave * 4 + ii;
      const int r = idx * 8 + lrow;
      int g = mBase + r; g = g > Mm1 ? Mm1 : g;
      GLD16(abase + (size_t)g * 256 + ka + lcol8, &As[idx * 512]);
    }
    // B: 12 issues; this wave does 3
#pragma unroll
    for (int ii = 0; ii < 3; ++ii) {
      const int idx = wave * 3 + ii;
      const int rb = idx * 8 + lrow;               // 0..95
      const int grow = (rb >> 5) * 256 + chBase + (rb & 31);
      GLD16(Wiou + (size_t)grow * 512 + kb + lcol8, &Bs[idx * 512]);
    }
    __syncthreads();
#pragma unroll
    for (int kk = 0; kk < 64; kk += 32) {
      const int lb = (kk >> 3) + quad;
      bf16x8 a[4];
#pragma unroll
      for (int mf = 0; mf < 4; ++mf) {
        const int rA = waveM * 64 + mf * 16 + lc;
        a[mf] = *(const bf16x8*)&As[rA * 64 + ((lb ^ (rA & 7)) << 3)];
      }
#pragma unroll
      for (int p = 0; p < 3; ++p) {
        const int rB = p * 32 + waveN * 16 + lc;
        bf16x8 b = *(const bf16x8*)&Bs[rB * 64 + ((lb ^ (rB & 7)) << 3)];
#pragma unroll
        for (int mf = 0; mf < 4; ++mf)
          acc[mf][p] = __builtin_amdgcn_mfma_f32_16x16x32_bf16(a[mf], b, acc[mf][p], 0, 0, 0);
      }
    }
    __syncthreads();
  };

#pragma unroll
  for (int kt = 0; kt < 256; kt += 64) ktile(Xb + (size_t)xbase * 256, kt, kt);
  if (K == 512) {
#pragma unroll
    for (int kt = 0; kt < 256; kt += 64) ktile(Hsin, kt, kt + 256);
  }

  const int ch = chBase + waveN * 16 + lc;
  const float bi = biou[ch], bo = biou[256 + ch], bu = biou[512 + ch];
#pragma unroll
  for (int mf = 0; mf < 4; ++mf) {
    const int row0 = mBase + waveM * 64 + mf * 16 + quad * 4;
    float hv[4] = {0.f, 0.f, 0.f, 0.f};
#pragma unroll
    for (int r = 0; r < 4; ++r) {
      const int rw = row0 + r;
      if (rw < M) {
        const float iv = acc[mf][0][r] + bi;
        const float ov = acc[mf][1][r] + bo;
        const float uv = acc[mf][2][r] + bu;
        float fc = 0.0f;
        if (FCs)      fc = FCs[(rw - mBase) * 32 + (ch - chBase)];
        else if (FCb) fc = (float)FCb[(size_t)rw * 256 + ch];
        const float cv = sigf(iv) * tanh_fast(uv) + fc;
        const float h1 = sigf(ov) * tanh_fast(cv);
        hv[r] = h1;
        Cst[(size_t)rw * 256 + ch] = (bf16)cv;
        H[(size_t)rw * 256 + ch] = (bf16)h1;
        if (isRoot && rw == 0) { out[ch] = cv; out[256 + ch] = h1; }
      }
    }
    if (row0 + 1 < M) Hsout[(size_t)(row0 >> 1) * 256 + ch] = (bf16)(hv[0] + hv[1]);
    if (row0 + 3 < M) Hsout[(size_t)((row0 >> 1) + 1) * 256 + ch] = (bf16)(hv[2] + hv[3]);
  }
}

// F tile over children: A[j] = [ Xb[parent(j)] | H[j] ], B = Wf (256 x 512).
// m97 profile: 128 x 128 tile, waves 2x2, acc 64. Fused: FC = f0*c0 + f1*c1.
// Used for large levels (15..11) only.
__device__ __forceinline__ void f_tile(
    bf16* __restrict__ As /*128*64*/, bf16* __restrict__ Bs /*128*64*/,
    const bf16* __restrict__ Xb, int xbase,
    const bf16* __restrict__ H, const bf16* __restrict__ Cc,
    const float* __restrict__ bfc, const bf16* __restrict__ Wf,
    bf16* __restrict__ FCb, int M2, int bx, int by)
{
  const int t = threadIdx.x;
  const int wave = t >> 6, lane = t & 63;
  const int quad = lane >> 4, lc = lane & 15;
  const int waveM = wave >> 1, waveN = wave & 1;
  const int mBase = by * 128;
  const int nBase = bx * 128;
  const int lrow = lane >> 3;
  const int lcol8 = ((lane & 7) ^ lrow) << 3;
  const int Mm1 = M2 - 1;
  f32x4 acc[4][4] = {};

  auto ktile = [&](bool xphase, int ka, int kb) {
#pragma unroll
    for (int ii = 0; ii < 4; ++ii) {
      const int idx = wave * 4 + ii;
      const int r = idx * 8 + lrow;
      int j = mBase + r; j = j > Mm1 ? Mm1 : j;
      const bf16* src = xphase ? Xb + (size_t)(xbase + (j >> 1)) * 256 + ka + lcol8
                               : H + (size_t)j * 256 + ka + lcol8;
      GLD16(src, &As[idx * 512]);
    }
#pragma unroll
    for (int ii = 0; ii < 4; ++ii) {
      const int idx = wave * 4 + ii;
      const int rb = idx * 8 + lrow;
      GLD16(Wf + (size_t)(nBase + rb) * 512 + kb + lcol8, &Bs[idx * 512]);
    }
    __syncthreads();
#pragma unroll
    for (int kk = 0; kk < 64; kk += 32) {
      const int lb = (kk >> 3) + quad;
      bf16x8 a[4];
#pragma unroll
      for (int mf = 0; mf < 4; ++mf) {
        const int rA = waveM * 64 + mf * 16 + lc;
        a[mf] = *(const bf16x8*)&As[rA * 64 + ((lb ^ (rA & 7)) << 3)];
      }
#pragma unroll
      for (int nf = 0; nf < 4; ++nf) {
        const int rB = waveN * 64 + nf * 16 + lc;
        bf16x8 b = *(const bf16x8*)&Bs[rB * 64 + ((lb ^ (rB & 7)) << 3)];
#pragma unroll
        for (int mf = 0; mf < 4; ++mf)
          acc[mf][nf] = __builtin_amdgcn_mfma_f32_16x16x32_bf16(a[mf], b, acc[mf][nf], 0, 0, 0);
      }
    }
    __syncthreads();
  };

#pragma unroll
  for (int kt = 0; kt < 256; kt += 64) ktile(true, kt, kt);
#pragma unroll
  for (int kt = 0; kt < 256; kt += 64) ktile(false, kt, kt + 256);

#pragma unroll
  for (int nf = 0; nf < 4; ++nf) {
    const int col = nBase + waveN * 64 + nf * 16 + lc;
    const float bv = bfc[col];
#pragma unroll
    for (int mf = 0; mf < 4; ++mf) {
      const int j0 = mBase + waveM * 64 + mf * 16 + quad * 4;
#pragma unroll
      for (int p = 0; p < 4; p += 2) {
        const int j = j0 + p;
        if (j < M2) {
          const float f0 = sigf(acc[mf][nf][p] + bv);
          const float f1 = sigf(acc[mf][nf][p + 1] + bv);
          const float c0 = (float)Cc[(size_t)j * 256 + col];
          const float c1 = (float)Cc[(size_t)(j + 1) * 256 + col];
          FCb[(size_t)(j >> 1) * 256 + col] = (bf16)(f0 * c0 + f1 * c1);
        }
      }
    }
  }
}

// Standalone wrappers for the large levels (grids as before).
__global__ __launch_bounds__(256) void iou_gemm(
    const bf16* __restrict__ Xb, int xbase,
    const bf16* __restrict__ Hsin, const bf16* __restrict__ FCb,
    const float* __restrict__ biou, const bf16* __restrict__ Wiou,
    bf16* __restrict__ Cst, bf16* __restrict__ H, bf16* __restrict__ Hsout,
    float* __restrict__ out, int M, int K, int isRoot)
{
  __shared__ bf16 As[128 * 64];   // 16 KB
  __shared__ bf16 Bs[96 * 64];    // 12 KB
  iou_tile(As, Bs, Xb, xbase, Hsin, FCb, nullptr, biou, Wiou, Cst, H, Hsout,
           out, M, K, isRoot, blockIdx.x, blockIdx.y);
}

__global__ __launch_bounds__(256) void f_gemm(
    const bf16* __restrict__ Xb, int xbase,
    const bf16* __restrict__ H, const bf16* __restrict__ Cc,
    const float* __restrict__ bfc, const bf16* __restrict__ Wf,
    bf16* __restrict__ FCb, int M2)
{
  __shared__ bf16 As[128 * 64];
  __shared__ bf16 Bs[128 * 64];
  f_tile(As, Bs, Xb, xbase, H, Cc, bfc, Wf, FCb, M2, blockIdx.x, blockIdx.y);
}

// Fused per-level kernel (levels FUSE_TOP..0). Block (bx,by) computes:
//   Phase F:  f-gate GEMM for child rows [2mBase, 2mBase+256) x cols
//             [chBase, chBase+32), K=512, A=[Xb[parent]|Hin], B=Wf rows.
//             FC = sig(f0)*c0 + sig(f1)*c1 -> FCs in LDS (f32, 128x32).
//   Phase IOU: standard iou tile, FC read from LDS.
// Partitioning is exact: 8 ch-blocks x 32 cols = 256 cols; row blocks are
// disjoint -> zero redundant f FLOPs. H/C ping-pong (Hin/Cin vs Hout/Cout)
// removes the cross-block WAR hazard within the dispatch.
__global__ __launch_bounds__(256) void fused_level(
    const bf16* __restrict__ Xb, int xbase,
    const bf16* __restrict__ Hin, const bf16* __restrict__ Cin,
    const bf16* __restrict__ Hsin,
    const float* __restrict__ biou, const float* __restrict__ bfc,
    const bf16* __restrict__ Wiou, const bf16* __restrict__ Wf,
    bf16* __restrict__ Hout, bf16* __restrict__ Cout, bf16* __restrict__ Hsout,
    float* __restrict__ out, int count, int isRoot)
{
  __shared__ bf16 As_f[256 * 64];   // 32 KB
  __shared__ bf16 Bs_f[32 * 64];    //  4 KB
  __shared__ float FCs[128 * 32];   // 16 KB
  __shared__ bf16 As_i[128 * 64];   // 16 KB
  __shared__ bf16 Bs_i[96 * 64];    // 12 KB   total 80 KB

  const int t = threadIdx.x;
  const int wave = t >> 6, lane = t & 63;
  const int quad = lane >> 4, lc = lane & 15;
  const int mBase = blockIdx.y * 128;
  const int chBase = blockIdx.x * 32;
  const int lrow = lane >> 3;
  const int lcol8 = ((lane & 7) ^ lrow) << 3;

  // ---- Phase F: 256 child rows x 32 cols, K = 512 ----
  const int M2 = count * 2;
  const int M2m1 = M2 - 1;
  f32x4 accf[4][2] = {};

  auto fktile = [&](bool xphase, int ka, int kb) {
    // A: 32 issues (8 child rows each); this wave does 8
#pragma unroll
    for (int ii = 0; ii < 8; ++ii) {
      const int idx = wave * 8 + ii;
      const int rl = idx * 8 + lrow;               // local child row 0..255
      int j = 2 * mBase + rl; j = j > M2m1 ? M2m1 : j;
      const bf16* src = xphase ? Xb + (size_t)(xbase + (j >> 1)) * 256 + ka + lcol8
                               : Hin + (size_t)j * 256 + ka + lcol8;
      GLD16(src, &As_f[idx * 512]);
    }
    // B: 4 issues (32 Wf rows); this wave does 1
    {
      const int rb = wave * 8 + lrow;              // 0..31
      GLD16(Wf + (size_t)(chBase + rb) * 512 + kb + lcol8, &Bs_f[wave * 512]);
    }
    __syncthreads();
#pragma unroll
    for (int kk = 0; kk < 64; kk += 32) {
      const int lb = (kk >> 3) + quad;
      bf16x8 a[4];
#pragma unroll
      for (int mf = 0; mf < 4; ++mf) {
        const int rA = wave * 64 + mf * 16 + lc;   // local child row
        a[mf] = *(const bf16x8*)&As_f[rA * 64 + ((lb ^ (rA & 7)) << 3)];
      }
#pragma unroll
      for (int nf = 0; nf < 2; ++nf) {
        const int rB = nf * 16 + lc;
        bf16x8 b = *(const bf16x8*)&Bs_f[rB * 64 + ((lb ^ (rB & 7)) << 3)];
#pragma unroll
        for (int mf = 0; mf < 4; ++mf)
          accf[mf][nf] = __builtin_amdgcn_mfma_f32_16x16x32_bf16(a[mf], b, accf[mf][nf], 0, 0, 0);
      }
    }
    __syncthreads();
  };

#pragma unroll
  for (int kt = 0; kt < 256; kt += 64) fktile(true, kt, kt);
#pragma unroll
  for (int kt = 0; kt < 256; kt += 64) fktile(false, kt, kt + 256);

  // F epilogue: FC pairs -> LDS (f32, rows rl>>1 in [0,128), cols 0..31)
#pragma unroll
  for (int nf = 0; nf < 2; ++nf) {
    const int ci = nf * 16 + lc;
    const float bv = bfc[chBase + ci];
#pragma unroll
    for (int mf = 0; mf < 4; ++mf) {
      const int rl0 = wave * 64 + mf * 16 + quad * 4;
#pragma unroll
      for (int p = 0; p < 4; p += 2) {
        const int rl = rl0 + p;                    // even
        const int j = 2 * mBase + rl;
        if (j + 1 < M2) {
          const float f0 = sigf(accf[mf][nf][p] + bv);
          const float f1 = sigf(accf[mf][nf][p + 1] + bv);
          const float c0 = (float)Cin[(size_t)j * 256 + chBase + ci];
          const float c1 = (float)Cin[(size_t)(j + 1) * 256 + chBase + ci];
          FCs[(rl >> 1) * 32 + ci] = f0 * c0 + f1 * c1;
        }
      }
    }
  }
  __syncthreads();   // FCs visible to all waves

  // ---- Phase IOU (FC from LDS) ----
  iou_tile(As_i, Bs_i, Xb, xbase, Hsin, nullptr, FCs, biou, Wiou,
           Cout, Hout, Hsout, out, count, 512, isRoot, blockIdx.x, blockIdx.y);
}

extern "C" void kernel_launch(void* const* d_in, const int* in_sizes, int n_in,
                              void* d_out, int out_size, void* d_ws, size_t ws_size,
                              hipStream_t stream)
{
  const float* X      = (const float*)d_in[0];
  const float* Wioux  = (const float*)d_in[1];
  const float* bioux  = (const float*)d_in[2];
  const float* Wiouh  = (const float*)d_in[3];
  const float* biouh  = (const float*)d_in[4];
  const float* Wfx    = (const float*)d_in[5];
  const float* bfx    = (const float*)d_in[6];
  const float* Wfh    = (const float*)d_in[7];
  const float* bfh    = (const float*)d_in[8];
  float* out = (float*)d_out;
  (void)in_sizes; (void)n_in; (void)out_size; (void)ws_size;

  // workspace: ~188 MB
  char* ws = (char*)d_ws;
  size_t off = 0;
  auto alloc = [&](size_t bytes) -> char* {
    char* p = ws + off;
    off += (bytes + 255) & ~(size_t)255;
    return p;
  };
  bf16*  Wiou = (bf16*)alloc((size_t)768 * 512 * 2);
  bf16*  Wf   = (bf16*)alloc((size_t)256 * 512 * 2);
  float* biou = (float*)alloc(768 * 4);
  float* bfc  = (float*)alloc(256 * 4);
  bf16*  Xb   = (bf16*)alloc((size_t)131071 * 256 * 2);  // 67.1 MB
  bf16*  H    = (bf16*)alloc((size_t)65536 * 256 * 2);   // 33.6 MB (level-local)
  bf16*  HsA  = (bf16*)alloc((size_t)32768 * 256 * 2);   // 16.8 MB
  bf16*  HsB  = (bf16*)alloc((size_t)32768 * 256 * 2);   // 16.8 MB
  bf16*  FCb  = (bf16*)alloc((size_t)32768 * 256 * 2);   // 16.8 MB (levels 15..11)
  bf16*  C    = (bf16*)alloc((size_t)65536 * 256 * 2);   // 33.6 MB (level-local)
  bf16*  H2   = (bf16*)alloc((size_t)2048 * 256 * 2);    // 1.05 MB (fused ping-pong)
  bf16*  C2   = (bf16*)alloc((size_t)2048 * 256 * 2);    // 1.05 MB

  prep_weights<<<2048, 256, 0, stream>>>(Wioux, Wiouh, Wfx, Wfh,
                                         bioux, biouh, bfx, bfh,
                                         Wiou, Wf, biou, bfc);
  convert_x<<<32768, 256, 0, stream>>>(X, Xb);

  // Leaf level: K=256 (x only); writes C/H rows [0,65536), HsA [0,32768)
  iou_gemm<<<dim3(8, 512), 256, 0, stream>>>(
      Xb, LEAF_START, HsA /*unused*/, nullptr, biou, Wiou,
      C, H, HsA, out, LEAF_COUNT, 256, 0);

  // Large internal levels 15..11 (two dispatches each; full grids).
  for (int lvl = 15; lvl > FUSE_TOP; --lvl) {
    const int count = 1 << lvl;
    const int s = count - 1;
    const int M2 = 2 * count;
    const bf16* Hsin = (lvl & 1) ? HsA : HsB;
    bf16* Hsout      = (lvl & 1) ? HsB : HsA;
    f_gemm<<<dim3(2, (M2 + 127) / 128), 256, 0, stream>>>(
        Xb, s, H, C, bfc, Wf, FCb, M2);
    iou_gemm<<<dim3(8, (count + 127) / 128), 256, 0, stream>>>(
        Xb, s, Hsin, FCb, biou, Wiou, C, H, Hsout, out, count, 512, 0);
  }

  // Fused levels 10..0: one dispatch per level; H/C ping-pong between the
  // big level-local buffers and the small H2/C2 pair.
  for (int lvl = FUSE_TOP; lvl >= 0; --lvl) {
    const int count = 1 << lvl;
    const int s = count - 1;
    const bf16* Hsin = (lvl & 1) ? HsA : HsB;
    bf16* Hsout      = (lvl & 1) ? HsB : HsA;
    const int pp = (FUSE_TOP - lvl) & 1;     // 0: in=H,C out=H2,C2 ; 1: reverse
    const bf16* Hin = pp ? H2 : H;
    const bf16* Cin = pp ? C2 : C;
    bf16* Hout      = pp ? H  : H2;
    bf16* Cout      = pp ? C  : C2;
    fused_level<<<dim3(8, (count + 127) / 128), 256, 0, stream>>>(
        Xb, s, Hin, Cin, Hsin, biou, bfc, Wiou, Wf,
        Hout, Cout, Hsout, out, count, lvl == 0);
  }
}

// Round 4
// 741.067 us; speedup vs baseline: 1.5452x; 1.0437x over previous
//
#include <hip/hip_runtime.h>
#include <hip/hip_bf16.h>
#include <cstdint>
#include <cstddef>

// ---------------------------------------------------------------------------
// ChildSumTreeLSTM, complete binary tree N=131071=2^17-1, dim 256.
// Round 8: r7 structure (fused levels 10..0, two-kernel levels 15..11 + leaf)
// + XCD-aware block swizzle on iou_gemm/f_gemm. r7 post-mortem: leaf FETCH
// 131.5 MB vs 37 MB ideal (3.9x A over-fetch) because the 8 chBase blocks
// sharing one A-row range round-robin onto 8 different (non-coherent) XCD L2s.
// Swizzle: 1-D grid, tile = (bid%8)*(T/8) + bid/8, bx fastest within a chunk
// -> A-sharing blocks colocate on one XCD; each XCD streams a contiguous
// by-chunk. Bijective (all grids are multiples of 8). Tile code untouched.
//   iou tile: 128 rows x 32 ch (96 cols = 3 parts x 32), acc 48 VGPR
//   fused LDS: 32+4+16+16+12 = 80 KB static
// ---------------------------------------------------------------------------

typedef __bf16 bf16;
typedef bf16 bf16x8 __attribute__((ext_vector_type(8)));
typedef float f32x4 __attribute__((ext_vector_type(4)));

#define LEAF_START 65535
#define LEAF_COUNT 65536
#define FUSE_TOP   10     // levels FUSE_TOP..0 use the fused one-dispatch-per-level kernel

__device__ __forceinline__ float sigf(float x) { return 1.0f / (1.0f + __expf(-x)); }
__device__ __forceinline__ float tanh_fast(float x) {
  return 1.0f - 2.0f / (__expf(2.0f * x) + 1.0f);
}

// async global->LDS, 16 B per lane, dest = base + lane*16
#define GLD16(g, l) __builtin_amdgcn_global_load_lds(                         \
    (const __attribute__((address_space(1))) void*)(g),                       \
    (__attribute__((address_space(3))) void*)(l), 16, 0, 0)

__global__ void prep_weights(const float* __restrict__ Wioux, const float* __restrict__ Wiouh,
                             const float* __restrict__ Wfx, const float* __restrict__ Wfh,
                             const float* __restrict__ bioux, const float* __restrict__ biouh,
                             const float* __restrict__ bfx, const float* __restrict__ bfh,
                             bf16* __restrict__ Wiou, bf16* __restrict__ Wf,
                             float* __restrict__ biou, float* __restrict__ bfc)
{
  const int el = blockIdx.x * 256 + threadIdx.x;   // 0 .. 524287
  if (el < 768 * 512) {
    const int r = el >> 9, c = el & 511;
    const float v = (c < 256) ? Wioux[r * 256 + c] : Wiouh[r * 256 + c - 256];
    Wiou[el] = (bf16)v;
  } else {
    const int e2 = el - 768 * 512;
    const int r = e2 >> 9, c = e2 & 511;
    const float v = (c < 256) ? Wfx[r * 256 + c] : Wfh[r * 256 + c - 256];
    Wf[e2] = (bf16)v;
  }
  if (el < 768)       biou[el] = bioux[el] + biouh[el];
  else if (el < 1024) bfc[el - 768] = bfx[el - 768] + bfh[el - 768];
}

__global__ void convert_x(const float* __restrict__ X, bf16* __restrict__ Xb)
{
  const int i = blockIdx.x * 256 + threadIdx.x;    // float4 index
  if (i < (131071 * 256) / 4) {
    const float4 v = ((const float4*)X)[i];
    union { ushort4 u; bf16 b[4]; } cv;
    cv.b[0] = (bf16)v.x; cv.b[1] = (bf16)v.y; cv.b[2] = (bf16)v.z; cv.b[3] = (bf16)v.w;
    ((ushort4*)Xb)[i] = cv.u;
  }
}

// IOU tile: A[M x K] = [ Xb[xbase+row] | Hsin[row] ], B = Wiou (768 x 512).
// Tile: 128 rows x 32 channels (96 cols: part*32+ch). Each wave: 64 rows
// (waveM) x 16 channels (waveN) x 3 parts -> lane-local i,o,u.
// FC source: FCs (LDS, fused path) > FCb (global) > none (leaf).
// Epilogue: c = sig(i)tanh(u) + FC; h = sig(o)tanh(c); emit C, H, Hsum.
__device__ __forceinline__ void iou_tile(
    bf16* __restrict__ As /*128*64*/, bf16* __restrict__ Bs /*96*64*/,
    const bf16* __restrict__ Xb, int xbase,
    const bf16* __restrict__ Hsin,
    const bf16* __restrict__ FCb, const float* FCs,
    const float* __restrict__ biou, const bf16* __restrict__ Wiou,
    bf16* __restrict__ Cst, bf16* __restrict__ H, bf16* __restrict__ Hsout,
    float* __restrict__ out, int M, int K, int isRoot, int bx, int by)
{
  const int t = threadIdx.x;
  const int wave = t >> 6, lane = t & 63;
  const int quad = lane >> 4, lc = lane & 15;
  const int waveM = wave >> 1, waveN = wave & 1;
  const int mBase = by * 128;
  const int chBase = bx * 32;
  const int lrow = lane >> 3;                      // 0..7
  const int lcol8 = ((lane & 7) ^ lrow) << 3;      // swizzled 8-elem block
  const int Mm1 = M - 1;
  f32x4 acc[4][3] = {};

  auto ktile = [&](const bf16* __restrict__ abase, int ka, int kb) {
    // A: 16 issues (8 rows each); this wave does 4
#pragma unroll
    for (int ii = 0; ii < 4; ++ii) {
      const int idx = wave * 4 + ii;
      const int r = idx * 8 + lrow;
      int g = mBase + r; g = g > Mm1 ? Mm1 : g;
      GLD16(abase + (size_t)g * 256 + ka + lcol8, &As[idx * 512]);
    }
    // B: 12 issues; this wave does 3
#pragma unroll
    for (int ii = 0; ii < 3; ++ii) {
      const int idx = wave * 3 + ii;
      const int rb = idx * 8 + lrow;               // 0..95
      const int grow = (rb >> 5) * 256 + chBase + (rb & 31);
      GLD16(Wiou + (size_t)grow * 512 + kb + lcol8, &Bs[idx * 512]);
    }
    __syncthreads();
#pragma unroll
    for (int kk = 0; kk < 64; kk += 32) {
      const int lb = (kk >> 3) + quad;
      bf16x8 a[4];
#pragma unroll
      for (int mf = 0; mf < 4; ++mf) {
        const int rA = waveM * 64 + mf * 16 + lc;
        a[mf] = *(const bf16x8*)&As[rA * 64 + ((lb ^ (rA & 7)) << 3)];
      }
#pragma unroll
      for (int p = 0; p < 3; ++p) {
        const int rB = p * 32 + waveN * 16 + lc;
        bf16x8 b = *(const bf16x8*)&Bs[rB * 64 + ((lb ^ (rB & 7)) << 3)];
#pragma unroll
        for (int mf = 0; mf < 4; ++mf)
          acc[mf][p] = __builtin_amdgcn_mfma_f32_16x16x32_bf16(a[mf], b, acc[mf][p], 0, 0, 0);
      }
    }
    __syncthreads();
  };

#pragma unroll
  for (int kt = 0; kt < 256; kt += 64) ktile(Xb + (size_t)xbase * 256, kt, kt);
  if (K == 512) {
#pragma unroll
    for (int kt = 0; kt < 256; kt += 64) ktile(Hsin, kt, kt + 256);
  }

  const int ch = chBase + waveN * 16 + lc;
  const float bi = biou[ch], bo = biou[256 + ch], bu = biou[512 + ch];
#pragma unroll
  for (int mf = 0; mf < 4; ++mf) {
    const int row0 = mBase + waveM * 64 + mf * 16 + quad * 4;
    float hv[4] = {0.f, 0.f, 0.f, 0.f};
#pragma unroll
    for (int r = 0; r < 4; ++r) {
      const int rw = row0 + r;
      if (rw < M) {
        const float iv = acc[mf][0][r] + bi;
        const float ov = acc[mf][1][r] + bo;
        const float uv = acc[mf][2][r] + bu;
        float fc = 0.0f;
        if (FCs)      fc = FCs[(rw - mBase) * 32 + (ch - chBase)];
        else if (FCb) fc = (float)FCb[(size_t)rw * 256 + ch];
        const float cv = sigf(iv) * tanh_fast(uv) + fc;
        const float h1 = sigf(ov) * tanh_fast(cv);
        hv[r] = h1;
        Cst[(size_t)rw * 256 + ch] = (bf16)cv;
        H[(size_t)rw * 256 + ch] = (bf16)h1;
        if (isRoot && rw == 0) { out[ch] = cv; out[256 + ch] = h1; }
      }
    }
    if (row0 + 1 < M) Hsout[(size_t)(row0 >> 1) * 256 + ch] = (bf16)(hv[0] + hv[1]);
    if (row0 + 3 < M) Hsout[(size_t)((row0 >> 1) + 1) * 256 + ch] = (bf16)(hv[2] + hv[3]);
  }
}

// F tile over children: A[j] = [ Xb[parent(j)] | H[j] ], B = Wf (256 x 512).
// m97 profile: 128 x 128 tile, waves 2x2, acc 64. Fused: FC = f0*c0 + f1*c1.
// Used for large levels (15..11) only.
__device__ __forceinline__ void f_tile(
    bf16* __restrict__ As /*128*64*/, bf16* __restrict__ Bs /*128*64*/,
    const bf16* __restrict__ Xb, int xbase,
    const bf16* __restrict__ H, const bf16* __restrict__ Cc,
    const float* __restrict__ bfc, const bf16* __restrict__ Wf,
    bf16* __restrict__ FCb, int M2, int bx, int by)
{
  const int t = threadIdx.x;
  const int wave = t >> 6, lane = t & 63;
  const int quad = lane >> 4, lc = lane & 15;
  const int waveM = wave >> 1, waveN = wave & 1;
  const int mBase = by * 128;
  const int nBase = bx * 128;
  const int lrow = lane >> 3;
  const int lcol8 = ((lane & 7) ^ lrow) << 3;
  const int Mm1 = M2 - 1;
  f32x4 acc[4][4] = {};

  auto ktile = [&](bool xphase, int ka, int kb) {
#pragma unroll
    for (int ii = 0; ii < 4; ++ii) {
      const int idx = wave * 4 + ii;
      const int r = idx * 8 + lrow;
      int j = mBase + r; j = j > Mm1 ? Mm1 : j;
      const bf16* src = xphase ? Xb + (size_t)(xbase + (j >> 1)) * 256 + ka + lcol8
                               : H + (size_t)j * 256 + ka + lcol8;
      GLD16(src, &As[idx * 512]);
    }
#pragma unroll
    for (int ii = 0; ii < 4; ++ii) {
      const int idx = wave * 4 + ii;
      const int rb = idx * 8 + lrow;
      GLD16(Wf + (size_t)(nBase + rb) * 512 + kb + lcol8, &Bs[idx * 512]);
    }
    __syncthreads();
#pragma unroll
    for (int kk = 0; kk < 64; kk += 32) {
      const int lb = (kk >> 3) + quad;
      bf16x8 a[4];
#pragma unroll
      for (int mf = 0; mf < 4; ++mf) {
        const int rA = waveM * 64 + mf * 16 + lc;
        a[mf] = *(const bf16x8*)&As[rA * 64 + ((lb ^ (rA & 7)) << 3)];
      }
#pragma unroll
      for (int nf = 0; nf < 4; ++nf) {
        const int rB = waveN * 64 + nf * 16 + lc;
        bf16x8 b = *(const bf16x8*)&Bs[rB * 64 + ((lb ^ (rB & 7)) << 3)];
#pragma unroll
        for (int mf = 0; mf < 4; ++mf)
          acc[mf][nf] = __builtin_amdgcn_mfma_f32_16x16x32_bf16(a[mf], b, acc[mf][nf], 0, 0, 0);
      }
    }
    __syncthreads();
  };

#pragma unroll
  for (int kt = 0; kt < 256; kt += 64) ktile(true, kt, kt);
#pragma unroll
  for (int kt = 0; kt < 256; kt += 64) ktile(false, kt, kt + 256);

#pragma unroll
  for (int nf = 0; nf < 4; ++nf) {
    const int col = nBase + waveN * 64 + nf * 16 + lc;
    const float bv = bfc[col];
#pragma unroll
    for (int mf = 0; mf < 4; ++mf) {
      const int j0 = mBase + waveM * 64 + mf * 16 + quad * 4;
#pragma unroll
      for (int p = 0; p < 4; p += 2) {
        const int j = j0 + p;
        if (j < M2) {
          const float f0 = sigf(acc[mf][nf][p] + bv);
          const float f1 = sigf(acc[mf][nf][p + 1] + bv);
          const float c0 = (float)Cc[(size_t)j * 256 + col];
          const float c1 = (float)Cc[(size_t)(j + 1) * 256 + col];
          FCb[(size_t)(j >> 1) * 256 + col] = (bf16)(f0 * c0 + f1 * c1);
        }
      }
    }
  }
}

// Standalone wrappers for the large levels. 1-D grid + XCD chunk swizzle:
// hw round-robins consecutive bids across 8 XCDs; tile = (bid%8)*(T/8)+bid/8
// gives XCD x the contiguous logical-tile chunk [x*T/8,(x+1)*T/8). With bx
// fastest in tile order, all blocks sharing an A-row range colocate per XCD.
__global__ __launch_bounds__(256) void iou_gemm(
    const bf16* __restrict__ Xb, int xbase,
    const bf16* __restrict__ Hsin, const bf16* __restrict__ FCb,
    const float* __restrict__ biou, const bf16* __restrict__ Wiou,
    bf16* __restrict__ Cst, bf16* __restrict__ H, bf16* __restrict__ Hsout,
    float* __restrict__ out, int M, int K, int isRoot)
{
  __shared__ bf16 As[128 * 64];   // 16 KB
  __shared__ bf16 Bs[96 * 64];    // 12 KB
  const int chunk = gridDim.x >> 3;                    // grid multiple of 8
  const int tile = (blockIdx.x & 7) * chunk + (blockIdx.x >> 3);
  iou_tile(As, Bs, Xb, xbase, Hsin, FCb, nullptr, biou, Wiou, Cst, H, Hsout,
           out, M, K, isRoot, tile & 7, tile >> 3);
}

__global__ __launch_bounds__(256) void f_gemm(
    const bf16* __restrict__ Xb, int xbase,
    const bf16* __restrict__ H, const bf16* __restrict__ Cc,
    const float* __restrict__ bfc, const bf16* __restrict__ Wf,
    bf16* __restrict__ FCb, int M2)
{
  __shared__ bf16 As[128 * 64];
  __shared__ bf16 Bs[128 * 64];
  const int chunk = gridDim.x >> 3;                    // grid multiple of 8
  const int tile = (blockIdx.x & 7) * chunk + (blockIdx.x >> 3);
  f_tile(As, Bs, Xb, xbase, H, Cc, bfc, Wf, FCb, M2, tile & 1, tile >> 1);
}

// Fused per-level kernel (levels FUSE_TOP..0). Block (bx,by) computes:
//   Phase F:  f-gate GEMM for child rows [2mBase, 2mBase+256) x cols
//             [chBase, chBase+32), K=512, A=[Xb[parent]|Hin], B=Wf rows.
//             FC = sig(f0)*c0 + sig(f1)*c1 -> FCs in LDS (f32, 128x32).
//   Phase IOU: standard iou tile, FC read from LDS.
// Partitioning is exact: 8 ch-blocks x 32 cols = 256 cols; row blocks are
// disjoint -> zero redundant f FLOPs. H/C ping-pong (Hin/Cin vs Hout/Cout)
// removes the cross-block WAR hazard within the dispatch.
__global__ __launch_bounds__(256) void fused_level(
    const bf16* __restrict__ Xb, int xbase,
    const bf16* __restrict__ Hin, const bf16* __restrict__ Cin,
    const bf16* __restrict__ Hsin,
    const float* __restrict__ biou, const float* __restrict__ bfc,
    const bf16* __restrict__ Wiou, const bf16* __restrict__ Wf,
    bf16* __restrict__ Hout, bf16* __restrict__ Cout, bf16* __restrict__ Hsout,
    float* __restrict__ out, int count, int isRoot)
{
  __shared__ bf16 As_f[256 * 64];   // 32 KB
  __shared__ bf16 Bs_f[32 * 64];    //  4 KB
  __shared__ float FCs[128 * 32];   // 16 KB
  __shared__ bf16 As_i[128 * 64];   // 16 KB
  __shared__ bf16 Bs_i[96 * 64];    // 12 KB   total 80 KB

  const int t = threadIdx.x;
  const int wave = t >> 6, lane = t & 63;
  const int quad = lane >> 4, lc = lane & 15;
  const int mBase = blockIdx.y * 128;
  const int chBase = blockIdx.x * 32;
  const int lrow = lane >> 3;
  const int lcol8 = ((lane & 7) ^ lrow) << 3;

  // ---- Phase F: 256 child rows x 32 cols, K = 512 ----
  const int M2 = count * 2;
  const int M2m1 = M2 - 1;
  f32x4 accf[4][2] = {};

  auto fktile = [&](bool xphase, int ka, int kb) {
    // A: 32 issues (8 child rows each); this wave does 8
#pragma unroll
    for (int ii = 0; ii < 8; ++ii) {
      const int idx = wave * 8 + ii;
      const int rl = idx * 8 + lrow;               // local child row 0..255
      int j = 2 * mBase + rl; j = j > M2m1 ? M2m1 : j;
      const bf16* src = xphase ? Xb + (size_t)(xbase + (j >> 1)) * 256 + ka + lcol8
                               : Hin + (size_t)j * 256 + ka + lcol8;
      GLD16(src, &As_f[idx * 512]);
    }
    // B: 4 issues (32 Wf rows); this wave does 1
    {
      const int rb = wave * 8 + lrow;              // 0..31
      GLD16(Wf + (size_t)(chBase + rb) * 512 + kb + lcol8, &Bs_f[wave * 512]);
    }
    __syncthreads();
#pragma unroll
    for (int kk = 0; kk < 64; kk += 32) {
      const int lb = (kk >> 3) + quad;
      bf16x8 a[4];
#pragma unroll
      for (int mf = 0; mf < 4; ++mf) {
        const int rA = wave * 64 + mf * 16 + lc;   // local child row
        a[mf] = *(const bf16x8*)&As_f[rA * 64 + ((lb ^ (rA & 7)) << 3)];
      }
#pragma unroll
      for (int nf = 0; nf < 2; ++nf) {
        const int rB = nf * 16 + lc;
        bf16x8 b = *(const bf16x8*)&Bs_f[rB * 64 + ((lb ^ (rB & 7)) << 3)];
#pragma unroll
        for (int mf = 0; mf < 4; ++mf)
          accf[mf][nf] = __builtin_amdgcn_mfma_f32_16x16x32_bf16(a[mf], b, accf[mf][nf], 0, 0, 0);
      }
    }
    __syncthreads();
  };

#pragma unroll
  for (int kt = 0; kt < 256; kt += 64) fktile(true, kt, kt);
#pragma unroll
  for (int kt = 0; kt < 256; kt += 64) fktile(false, kt, kt + 256);

  // F epilogue: FC pairs -> LDS (f32, rows rl>>1 in [0,128), cols 0..31)
#pragma unroll
  for (int nf = 0; nf < 2; ++nf) {
    const int ci = nf * 16 + lc;
    const float bv = bfc[chBase + ci];
#pragma unroll
    for (int mf = 0; mf < 4; ++mf) {
      const int rl0 = wave * 64 + mf * 16 + quad * 4;
#pragma unroll
      for (int p = 0; p < 4; p += 2) {
        const int rl = rl0 + p;                    // even
        const int j = 2 * mBase + rl;
        if (j + 1 < M2) {
          const float f0 = sigf(accf[mf][nf][p] + bv);
          const float f1 = sigf(accf[mf][nf][p + 1] + bv);
          const float c0 = (float)Cin[(size_t)j * 256 + chBase + ci];
          const float c1 = (float)Cin[(size_t)(j + 1) * 256 + chBase + ci];
          FCs[(rl >> 1) * 32 + ci] = f0 * c0 + f1 * c1;
        }
      }
    }
  }
  __syncthreads();   // FCs visible to all waves

  // ---- Phase IOU (FC from LDS) ----
  iou_tile(As_i, Bs_i, Xb, xbase, Hsin, nullptr, FCs, biou, Wiou,
           Cout, Hout, Hsout, out, count, 512, isRoot, blockIdx.x, blockIdx.y);
}

extern "C" void kernel_launch(void* const* d_in, const int* in_sizes, int n_in,
                              void* d_out, int out_size, void* d_ws, size_t ws_size,
                              hipStream_t stream)
{
  const float* X      = (const float*)d_in[0];
  const float* Wioux  = (const float*)d_in[1];
  const float* bioux  = (const float*)d_in[2];
  const float* Wiouh  = (const float*)d_in[3];
  const float* biouh  = (const float*)d_in[4];
  const float* Wfx    = (const float*)d_in[5];
  const float* bfx    = (const float*)d_in[6];
  const float* Wfh    = (const float*)d_in[7];
  const float* bfh    = (const float*)d_in[8];
  float* out = (float*)d_out;
  (void)in_sizes; (void)n_in; (void)out_size; (void)ws_size;

  // workspace: ~188 MB
  char* ws = (char*)d_ws;
  size_t off = 0;
  auto alloc = [&](size_t bytes) -> char* {
    char* p = ws + off;
    off += (bytes + 255) & ~(size_t)255;
    return p;
  };
  bf16*  Wiou = (bf16*)alloc((size_t)768 * 512 * 2);
  bf16*  Wf   = (bf16*)alloc((size_t)256 * 512 * 2);
  float* biou = (float*)alloc(768 * 4);
  float* bfc  = (float*)alloc(256 * 4);
  bf16*  Xb   = (bf16*)alloc((size_t)131071 * 256 * 2);  // 67.1 MB
  bf16*  H    = (bf16*)alloc((size_t)65536 * 256 * 2);   // 33.6 MB (level-local)
  bf16*  HsA  = (bf16*)alloc((size_t)32768 * 256 * 2);   // 16.8 MB
  bf16*  HsB  = (bf16*)alloc((size_t)32768 * 256 * 2);   // 16.8 MB
  bf16*  FCb  = (bf16*)alloc((size_t)32768 * 256 * 2);   // 16.8 MB (levels 15..11)
  bf16*  C    = (bf16*)alloc((size_t)65536 * 256 * 2);   // 33.6 MB (level-local)
  bf16*  H2   = (bf16*)alloc((size_t)2048 * 256 * 2);    // 1.05 MB (fused ping-pong)
  bf16*  C2   = (bf16*)alloc((size_t)2048 * 256 * 2);    // 1.05 MB

  prep_weights<<<2048, 256, 0, stream>>>(Wioux, Wiouh, Wfx, Wfh,
                                         bioux, biouh, bfx, bfh,
                                         Wiou, Wf, biou, bfc);
  convert_x<<<32768, 256, 0, stream>>>(X, Xb);

  // Leaf level: K=256 (x only); writes C/H rows [0,65536), HsA [0,32768)
  iou_gemm<<<8 * 512, 256, 0, stream>>>(
      Xb, LEAF_START, HsA /*unused*/, nullptr, biou, Wiou,
      C, H, HsA, out, LEAF_COUNT, 256, 0);

  // Large internal levels 15..11 (two dispatches each; 1-D swizzled grids).
  for (int lvl = 15; lvl > FUSE_TOP; --lvl) {
    const int count = 1 << lvl;
    const int s = count - 1;
    const int M2 = 2 * count;
    const bf16* Hsin = (lvl & 1) ? HsA : HsB;
    bf16* Hsout      = (lvl & 1) ? HsB : HsA;
    f_gemm<<<2 * (M2 / 128), 256, 0, stream>>>(
        Xb, s, H, C, bfc, Wf, FCb, M2);
    iou_gemm<<<8 * (count / 128), 256, 0, stream>>>(
        Xb, s, Hsin, FCb, biou, Wiou, C, H, Hsout, out, count, 512, 0);
  }

  // Fused levels 10..0: one dispatch per level; H/C ping-pong between the
  // big level-local buffers and the small H2/C2 pair.
  for (int lvl = FUSE_TOP; lvl >= 0; --lvl) {
    const int count = 1 << lvl;
    const int s = count - 1;
    const bf16* Hsin = (lvl & 1) ? HsA : HsB;
    bf16* Hsout      = (lvl & 1) ? HsB : HsA;
    const int pp = (FUSE_TOP - lvl) & 1;     // 0: in=H,C out=H2,C2 ; 1: reverse
    const bf16* Hin = pp ? H2 : H;
    const bf16* Cin = pp ? C2 : C;
    bf16* Hout      = pp ? H  : H2;
    bf16* Cout      = pp ? C  : C2;
    fused_level<<<dim3(8, (count + 127) / 128), 256, 0, stream>>>(
        Xb, s, Hin, Cin, Hsin, biou, bfc, Wiou, Wf,
        Hout, Cout, Hsout, out, count, lvl == 0);
  }
}

// Round 5
// 698.894 us; speedup vs baseline: 1.6385x; 1.0603x over previous
//
#include <hip/hip_runtime.h>
#include <hip/hip_bf16.h>
#include <cstdint>
#include <cstddef>

// ---------------------------------------------------------------------------
// ChildSumTreeLSTM, complete binary tree N=131071=2^17-1, dim 256.
// Round 9: r8 structure + two tail changes:
//  (1) fused_level INTERLEAVES F and IOU ktiles (IOU inputs Xb/Hsin do not
//      depend on F; only the FC epilogue does). 16 barrier-serialized stages
//      -> 8 stages with 2x work each; small-level latency ~halves.
//  (2) FUSE_TOP 10 -> 12 (fused kernel is count-generic; H2/C2 sized 4096
//      rows). Removes 4 dispatches + FCb roundtrips at lvl 12/11.
// Leaf + levels 15..13 keep the two-kernel path with XCD chunk swizzle (r8).
//   fused LDS: 32+4+16+12+16 = 80 KB static; acc 80 VGPR (F 32 + IOU 48)
// ---------------------------------------------------------------------------

typedef __bf16 bf16;
typedef bf16 bf16x8 __attribute__((ext_vector_type(8)));
typedef float f32x4 __attribute__((ext_vector_type(4)));

#define LEAF_START 65535
#define LEAF_COUNT 65536
#define FUSE_TOP   12     // levels FUSE_TOP..0 use the fused one-dispatch-per-level kernel

__device__ __forceinline__ float sigf(float x) { return 1.0f / (1.0f + __expf(-x)); }
__device__ __forceinline__ float tanh_fast(float x) {
  return 1.0f - 2.0f / (__expf(2.0f * x) + 1.0f);
}

// async global->LDS, 16 B per lane, dest = base + lane*16
#define GLD16(g, l) __builtin_amdgcn_global_load_lds(                         \
    (const __attribute__((address_space(1))) void*)(g),                       \
    (__attribute__((address_space(3))) void*)(l), 16, 0, 0)

__global__ void prep_weights(const float* __restrict__ Wioux, const float* __restrict__ Wiouh,
                             const float* __restrict__ Wfx, const float* __restrict__ Wfh,
                             const float* __restrict__ bioux, const float* __restrict__ biouh,
                             const float* __restrict__ bfx, const float* __restrict__ bfh,
                             bf16* __restrict__ Wiou, bf16* __restrict__ Wf,
                             float* __restrict__ biou, float* __restrict__ bfc)
{
  const int el = blockIdx.x * 256 + threadIdx.x;   // 0 .. 524287
  if (el < 768 * 512) {
    const int r = el >> 9, c = el & 511;
    const float v = (c < 256) ? Wioux[r * 256 + c] : Wiouh[r * 256 + c - 256];
    Wiou[el] = (bf16)v;
  } else {
    const int e2 = el - 768 * 512;
    const int r = e2 >> 9, c = e2 & 511;
    const float v = (c < 256) ? Wfx[r * 256 + c] : Wfh[r * 256 + c - 256];
    Wf[e2] = (bf16)v;
  }
  if (el < 768)       biou[el] = bioux[el] + biouh[el];
  else if (el < 1024) bfc[el - 768] = bfx[el - 768] + bfh[el - 768];
}

__global__ void convert_x(const float* __restrict__ X, bf16* __restrict__ Xb)
{
  const int i = blockIdx.x * 256 + threadIdx.x;    // float4 index
  if (i < (131071 * 256) / 4) {
    const float4 v = ((const float4*)X)[i];
    union { ushort4 u; bf16 b[4]; } cv;
    cv.b[0] = (bf16)v.x; cv.b[1] = (bf16)v.y; cv.b[2] = (bf16)v.z; cv.b[3] = (bf16)v.w;
    ((ushort4*)Xb)[i] = cv.u;
  }
}

// IOU tile: A[M x K] = [ Xb[xbase+row] | Hsin[row] ], B = Wiou (768 x 512).
// Tile: 128 rows x 32 channels (96 cols: part*32+ch). Each wave: 64 rows
// (waveM) x 16 channels (waveN) x 3 parts -> lane-local i,o,u.
// Epilogue: c = sig(i)tanh(u) + FC; h = sig(o)tanh(c); emit C, H, Hsum.
__device__ __forceinline__ void iou_tile(
    bf16* __restrict__ As /*128*64*/, bf16* __restrict__ Bs /*96*64*/,
    const bf16* __restrict__ Xb, int xbase,
    const bf16* __restrict__ Hsin, const bf16* __restrict__ FCb,
    const float* __restrict__ biou, const bf16* __restrict__ Wiou,
    bf16* __restrict__ Cst, bf16* __restrict__ H, bf16* __restrict__ Hsout,
    float* __restrict__ out, int M, int K, int isRoot, int bx, int by)
{
  const int t = threadIdx.x;
  const int wave = t >> 6, lane = t & 63;
  const int quad = lane >> 4, lc = lane & 15;
  const int waveM = wave >> 1, waveN = wave & 1;
  const int mBase = by * 128;
  const int chBase = bx * 32;
  const int lrow = lane >> 3;                      // 0..7
  const int lcol8 = ((lane & 7) ^ lrow) << 3;      // swizzled 8-elem block
  const int Mm1 = M - 1;
  f32x4 acc[4][3] = {};

  auto ktile = [&](const bf16* __restrict__ abase, int ka, int kb) {
#pragma unroll
    for (int ii = 0; ii < 4; ++ii) {
      const int idx = wave * 4 + ii;
      const int r = idx * 8 + lrow;
      int g = mBase + r; g = g > Mm1 ? Mm1 : g;
      GLD16(abase + (size_t)g * 256 + ka + lcol8, &As[idx * 512]);
    }
#pragma unroll
    for (int ii = 0; ii < 3; ++ii) {
      const int idx = wave * 3 + ii;
      const int rb = idx * 8 + lrow;               // 0..95
      const int grow = (rb >> 5) * 256 + chBase + (rb & 31);
      GLD16(Wiou + (size_t)grow * 512 + kb + lcol8, &Bs[idx * 512]);
    }
    __syncthreads();
#pragma unroll
    for (int kk = 0; kk < 64; kk += 32) {
      const int lb = (kk >> 3) + quad;
      bf16x8 a[4];
#pragma unroll
      for (int mf = 0; mf < 4; ++mf) {
        const int rA = waveM * 64 + mf * 16 + lc;
        a[mf] = *(const bf16x8*)&As[rA * 64 + ((lb ^ (rA & 7)) << 3)];
      }
#pragma unroll
      for (int p = 0; p < 3; ++p) {
        const int rB = p * 32 + waveN * 16 + lc;
        bf16x8 b = *(const bf16x8*)&Bs[rB * 64 + ((lb ^ (rB & 7)) << 3)];
#pragma unroll
        for (int mf = 0; mf < 4; ++mf)
          acc[mf][p] = __builtin_amdgcn_mfma_f32_16x16x32_bf16(a[mf], b, acc[mf][p], 0, 0, 0);
      }
    }
    __syncthreads();
  };

#pragma unroll
  for (int kt = 0; kt < 256; kt += 64) ktile(Xb + (size_t)xbase * 256, kt, kt);
  if (K == 512) {
#pragma unroll
    for (int kt = 0; kt < 256; kt += 64) ktile(Hsin, kt, kt + 256);
  }

  const int ch = chBase + waveN * 16 + lc;
  const float bi = biou[ch], bo = biou[256 + ch], bu = biou[512 + ch];
#pragma unroll
  for (int mf = 0; mf < 4; ++mf) {
    const int row0 = mBase + waveM * 64 + mf * 16 + quad * 4;
    float hv[4] = {0.f, 0.f, 0.f, 0.f};
#pragma unroll
    for (int r = 0; r < 4; ++r) {
      const int rw = row0 + r;
      if (rw < M) {
        const float iv = acc[mf][0][r] + bi;
        const float ov = acc[mf][1][r] + bo;
        const float uv = acc[mf][2][r] + bu;
        const float fc = FCb ? (float)FCb[(size_t)rw * 256 + ch] : 0.0f;
        const float cv = sigf(iv) * tanh_fast(uv) + fc;
        const float h1 = sigf(ov) * tanh_fast(cv);
        hv[r] = h1;
        Cst[(size_t)rw * 256 + ch] = (bf16)cv;
        H[(size_t)rw * 256 + ch] = (bf16)h1;
        if (isRoot && rw == 0) { out[ch] = cv; out[256 + ch] = h1; }
      }
    }
    if (row0 + 1 < M) Hsout[(size_t)(row0 >> 1) * 256 + ch] = (bf16)(hv[0] + hv[1]);
    if (row0 + 3 < M) Hsout[(size_t)((row0 >> 1) + 1) * 256 + ch] = (bf16)(hv[2] + hv[3]);
  }
}

// F tile over children: A[j] = [ Xb[parent(j)] | H[j] ], B = Wf (256 x 512).
// m97 profile: 128 x 128 tile, waves 2x2, acc 64. Used for levels 15..13.
__device__ __forceinline__ void f_tile(
    bf16* __restrict__ As /*128*64*/, bf16* __restrict__ Bs /*128*64*/,
    const bf16* __restrict__ Xb, int xbase,
    const bf16* __restrict__ H, const bf16* __restrict__ Cc,
    const float* __restrict__ bfc, const bf16* __restrict__ Wf,
    bf16* __restrict__ FCb, int M2, int bx, int by)
{
  const int t = threadIdx.x;
  const int wave = t >> 6, lane = t & 63;
  const int quad = lane >> 4, lc = lane & 15;
  const int waveM = wave >> 1, waveN = wave & 1;
  const int mBase = by * 128;
  const int nBase = bx * 128;
  const int lrow = lane >> 3;
  const int lcol8 = ((lane & 7) ^ lrow) << 3;
  const int Mm1 = M2 - 1;
  f32x4 acc[4][4] = {};

  auto ktile = [&](bool xphase, int ka, int kb) {
#pragma unroll
    for (int ii = 0; ii < 4; ++ii) {
      const int idx = wave * 4 + ii;
      const int r = idx * 8 + lrow;
      int j = mBase + r; j = j > Mm1 ? Mm1 : j;
      const bf16* src = xphase ? Xb + (size_t)(xbase + (j >> 1)) * 256 + ka + lcol8
                               : H + (size_t)j * 256 + ka + lcol8;
      GLD16(src, &As[idx * 512]);
    }
#pragma unroll
    for (int ii = 0; ii < 4; ++ii) {
      const int idx = wave * 4 + ii;
      const int rb = idx * 8 + lrow;
      GLD16(Wf + (size_t)(nBase + rb) * 512 + kb + lcol8, &Bs[idx * 512]);
    }
    __syncthreads();
#pragma unroll
    for (int kk = 0; kk < 64; kk += 32) {
      const int lb = (kk >> 3) + quad;
      bf16x8 a[4];
#pragma unroll
      for (int mf = 0; mf < 4; ++mf) {
        const int rA = waveM * 64 + mf * 16 + lc;
        a[mf] = *(const bf16x8*)&As[rA * 64 + ((lb ^ (rA & 7)) << 3)];
      }
#pragma unroll
      for (int nf = 0; nf < 4; ++nf) {
        const int rB = waveN * 64 + nf * 16 + lc;
        bf16x8 b = *(const bf16x8*)&Bs[rB * 64 + ((lb ^ (rB & 7)) << 3)];
#pragma unroll
        for (int mf = 0; mf < 4; ++mf)
          acc[mf][nf] = __builtin_amdgcn_mfma_f32_16x16x32_bf16(a[mf], b, acc[mf][nf], 0, 0, 0);
      }
    }
    __syncthreads();
  };

#pragma unroll
  for (int kt = 0; kt < 256; kt += 64) ktile(true, kt, kt);
#pragma unroll
  for (int kt = 0; kt < 256; kt += 64) ktile(false, kt, kt + 256);

#pragma unroll
  for (int nf = 0; nf < 4; ++nf) {
    const int col = nBase + waveN * 64 + nf * 16 + lc;
    const float bv = bfc[col];
#pragma unroll
    for (int mf = 0; mf < 4; ++mf) {
      const int j0 = mBase + waveM * 64 + mf * 16 + quad * 4;
#pragma unroll
      for (int p = 0; p < 4; p += 2) {
        const int j = j0 + p;
        if (j < M2) {
          const float f0 = sigf(acc[mf][nf][p] + bv);
          const float f1 = sigf(acc[mf][nf][p + 1] + bv);
          const float c0 = (float)Cc[(size_t)j * 256 + col];
          const float c1 = (float)Cc[(size_t)(j + 1) * 256 + col];
          FCb[(size_t)(j >> 1) * 256 + col] = (bf16)(f0 * c0 + f1 * c1);
        }
      }
    }
  }
}

// Standalone wrappers for the large levels. 1-D grid + XCD chunk swizzle (r8).
__global__ __launch_bounds__(256) void iou_gemm(
    const bf16* __restrict__ Xb, int xbase,
    const bf16* __restrict__ Hsin, const bf16* __restrict__ FCb,
    const float* __restrict__ biou, const bf16* __restrict__ Wiou,
    bf16* __restrict__ Cst, bf16* __restrict__ H, bf16* __restrict__ Hsout,
    float* __restrict__ out, int M, int K, int isRoot)
{
  __shared__ bf16 As[128 * 64];   // 16 KB
  __shared__ bf16 Bs[96 * 64];    // 12 KB
  const int chunk = gridDim.x >> 3;                    // grid multiple of 8
  const int tile = (blockIdx.x & 7) * chunk + (blockIdx.x >> 3);
  iou_tile(As, Bs, Xb, xbase, Hsin, FCb, biou, Wiou, Cst, H, Hsout,
           out, M, K, isRoot, tile & 7, tile >> 3);
}

__global__ __launch_bounds__(256) void f_gemm(
    const bf16* __restrict__ Xb, int xbase,
    const bf16* __restrict__ H, const bf16* __restrict__ Cc,
    const float* __restrict__ bfc, const bf16* __restrict__ Wf,
    bf16* __restrict__ FCb, int M2)
{
  __shared__ bf16 As[128 * 64];
  __shared__ bf16 Bs[128 * 64];
  const int chunk = gridDim.x >> 3;                    // grid multiple of 8
  const int tile = (blockIdx.x & 7) * chunk + (blockIdx.x >> 3);
  f_tile(As, Bs, Xb, xbase, H, Cc, bfc, Wf, FCb, M2, tile & 1, tile >> 1);
}

// Fused per-level kernel (levels FUSE_TOP..0), INTERLEAVED F+IOU.
// Block (bx,by):
//   F:   f-gate GEMM, child rows [2mBase, 2mBase+256) x cols [chBase,+32),
//        K=512, A=[Xb[parent]|Hin], B=Wf rows. -> FC in LDS.
//   IOU: 128 rows x 32 ch x 3 parts, K=512, A=[Xb|Hsin], B=Wiou rows.
// IOU's A inputs (Xb, Hsin) do NOT depend on F -> both GEMMs' kt-th K-slices
// are staged together and computed after ONE barrier: 8 stages instead of 16.
// Only the FC epilogue consumes F's result (one extra __syncthreads).
// H/C ping-pong (Hin/Cin vs Hout/Cout) removes the cross-block WAR hazard.
__global__ __launch_bounds__(256) void fused_level(
    const bf16* __restrict__ Xb, int xbase,
    const bf16* __restrict__ Hin, const bf16* __restrict__ Cin,
    const bf16* __restrict__ Hsin,
    const float* __restrict__ biou, const float* __restrict__ bfc,
    const bf16* __restrict__ Wiou, const bf16* __restrict__ Wf,
    bf16* __restrict__ Hout, bf16* __restrict__ Cout, bf16* __restrict__ Hsout,
    float* __restrict__ out, int count, int isRoot)
{
  __shared__ bf16 As_f[256 * 64];   // 32 KB
  __shared__ bf16 Bs_f[32 * 64];    //  4 KB
  __shared__ bf16 As_i[128 * 64];   // 16 KB
  __shared__ bf16 Bs_i[96 * 64];    // 12 KB
  __shared__ float FCs[128 * 32];   // 16 KB   total 80 KB

  const int t = threadIdx.x;
  const int wave = t >> 6, lane = t & 63;
  const int quad = lane >> 4, lc = lane & 15;
  const int waveM = wave >> 1, waveN = wave & 1;
  const int mBase = blockIdx.y * 128;
  const int chBase = blockIdx.x * 32;
  const int lrow = lane >> 3;
  const int lcol8 = ((lane & 7) ^ lrow) << 3;

  const int M = count, Mm1 = M - 1;
  const int M2 = count * 2, M2m1 = M2 - 1;

  f32x4 accf[4][2] = {};   // F: 64 child rows/wave x 32 cols
  f32x4 acci[4][3] = {};   // IOU: 64 rows (waveM) x 16 ch (waveN) x 3 parts

  // 8 combined stages; stage kt covers K-slice [kt*64, kt*64+64) of 512.
  // kt<4: x-part (A from Xb); kt>=4: h-part (A from Hin / Hsin).
#pragma unroll
  for (int kt = 0; kt < 8; ++kt) {
    const bool xph = kt < 4;
    const int ka = (kt & 3) * 64;        // source-row K offset
    const int kb = kt * 64;              // weight-row K offset (0..448)
    // F A: 32 issues (8/wave), 256 child rows
#pragma unroll
    for (int ii = 0; ii < 8; ++ii) {
      const int idx = wave * 8 + ii;
      const int rl = idx * 8 + lrow;
      int j = 2 * mBase + rl; j = j > M2m1 ? M2m1 : j;
      const bf16* src = xph ? Xb + (size_t)(xbase + (j >> 1)) * 256 + ka + lcol8
                            : Hin + (size_t)j * 256 + ka + lcol8;
      GLD16(src, &As_f[idx * 512]);
    }
    // F B: 4 issues (1/wave), 32 Wf rows
    {
      const int rb = wave * 8 + lrow;
      GLD16(Wf + (size_t)(chBase + rb) * 512 + kb + lcol8, &Bs_f[wave * 512]);
    }
    // IOU A: 16 issues (4/wave), 128 node rows
#pragma unroll
    for (int ii = 0; ii < 4; ++ii) {
      const int idx = wave * 4 + ii;
      const int r = idx * 8 + lrow;
      int g = mBase + r; g = g > Mm1 ? Mm1 : g;
      const bf16* src = xph ? Xb + (size_t)(xbase + g) * 256 + ka + lcol8
                            : Hsin + (size_t)g * 256 + ka + lcol8;
      GLD16(src, &As_i[idx * 512]);
    }
    // IOU B: 12 issues (3/wave), 96 Wiou rows (3 parts x 32 ch)
#pragma unroll
    for (int ii = 0; ii < 3; ++ii) {
      const int idx = wave * 3 + ii;
      const int rb = idx * 8 + lrow;               // 0..95
      const int grow = (rb >> 5) * 256 + chBase + (rb & 31);
      GLD16(Wiou + (size_t)grow * 512 + kb + lcol8, &Bs_i[idx * 512]);
    }
    __syncthreads();
#pragma unroll
    for (int kk = 0; kk < 64; kk += 32) {
      const int lb = (kk >> 3) + quad;
      // F MFMAs (16 per stage-half)
      bf16x8 af[4];
#pragma unroll
      for (int mf = 0; mf < 4; ++mf) {
        const int rA = wave * 64 + mf * 16 + lc;
        af[mf] = *(const bf16x8*)&As_f[rA * 64 + ((lb ^ (rA & 7)) << 3)];
      }
#pragma unroll
      for (int nf = 0; nf < 2; ++nf) {
        const int rB = nf * 16 + lc;
        bf16x8 b = *(const bf16x8*)&Bs_f[rB * 64 + ((lb ^ (rB & 7)) << 3)];
#pragma unroll
        for (int mf = 0; mf < 4; ++mf)
          accf[mf][nf] = __builtin_amdgcn_mfma_f32_16x16x32_bf16(af[mf], b, accf[mf][nf], 0, 0, 0);
      }
      // IOU MFMAs (24 per stage-half)
      bf16x8 ai[4];
#pragma unroll
      for (int mf = 0; mf < 4; ++mf) {
        const int rA = waveM * 64 + mf * 16 + lc;
        ai[mf] = *(const bf16x8*)&As_i[rA * 64 + ((lb ^ (rA & 7)) << 3)];
      }
#pragma unroll
      for (int p = 0; p < 3; ++p) {
        const int rB = p * 32 + waveN * 16 + lc;
        bf16x8 b = *(const bf16x8*)&Bs_i[rB * 64 + ((lb ^ (rB & 7)) << 3)];
#pragma unroll
        for (int mf = 0; mf < 4; ++mf)
          acci[mf][p] = __builtin_amdgcn_mfma_f32_16x16x32_bf16(ai[mf], b, acci[mf][p], 0, 0, 0);
      }
    }
    __syncthreads();
  }

  // F epilogue: FC pairs -> LDS (f32, rows rl>>1 in [0,128), cols 0..31)
#pragma unroll
  for (int nf = 0; nf < 2; ++nf) {
    const int ci = nf * 16 + lc;
    const float bv = bfc[chBase + ci];
#pragma unroll
    for (int mf = 0; mf < 4; ++mf) {
      const int rl0 = wave * 64 + mf * 16 + quad * 4;
#pragma unroll
      for (int p = 0; p < 4; p += 2) {
        const int rl = rl0 + p;                    // even
        const int j = 2 * mBase + rl;
        if (j + 1 < M2) {
          const float f0 = sigf(accf[mf][nf][p] + bv);
          const float f1 = sigf(accf[mf][nf][p + 1] + bv);
          const float c0 = (float)Cin[(size_t)j * 256 + chBase + ci];
          const float c1 = (float)Cin[(size_t)(j + 1) * 256 + chBase + ci];
          FCs[(rl >> 1) * 32 + ci] = f0 * c0 + f1 * c1;
        }
      }
    }
  }
  __syncthreads();   // FCs visible to all waves

  // IOU epilogue (FC from LDS)
  const int ch = chBase + waveN * 16 + lc;
  const float bi = biou[ch], bo = biou[256 + ch], bu = biou[512 + ch];
#pragma unroll
  for (int mf = 0; mf < 4; ++mf) {
    const int row0 = mBase + waveM * 64 + mf * 16 + quad * 4;
    float hv[4] = {0.f, 0.f, 0.f, 0.f};
#pragma unroll
    for (int r = 0; r < 4; ++r) {
      const int rw = row0 + r;
      if (rw < M) {
        const float iv = acci[mf][0][r] + bi;
        const float ov = acci[mf][1][r] + bo;
        const float uv = acci[mf][2][r] + bu;
        const float fc = FCs[(rw - mBase) * 32 + (ch - chBase)];
        const float cv = sigf(iv) * tanh_fast(uv) + fc;
        const float h1 = sigf(ov) * tanh_fast(cv);
        hv[r] = h1;
        Cout[(size_t)rw * 256 + ch] = (bf16)cv;
        Hout[(size_t)rw * 256 + ch] = (bf16)h1;
        if (isRoot && rw == 0) { out[ch] = cv; out[256 + ch] = h1; }
      }
    }
    if (row0 + 1 < M) Hsout[(size_t)(row0 >> 1) * 256 + ch] = (bf16)(hv[0] + hv[1]);
    if (row0 + 3 < M) Hsout[(size_t)((row0 >> 1) + 1) * 256 + ch] = (bf16)(hv[2] + hv[3]);
  }
}

extern "C" void kernel_launch(void* const* d_in, const int* in_sizes, int n_in,
                              void* d_out, int out_size, void* d_ws, size_t ws_size,
                              hipStream_t stream)
{
  const float* X      = (const float*)d_in[0];
  const float* Wioux  = (const float*)d_in[1];
  const float* bioux  = (const float*)d_in[2];
  const float* Wiouh  = (const float*)d_in[3];
  const float* biouh  = (const float*)d_in[4];
  const float* Wfx    = (const float*)d_in[5];
  const float* bfx    = (const float*)d_in[6];
  const float* Wfh    = (const float*)d_in[7];
  const float* bfh    = (const float*)d_in[8];
  float* out = (float*)d_out;
  (void)in_sizes; (void)n_in; (void)out_size; (void)ws_size;

  // workspace: ~192 MB
  char* ws = (char*)d_ws;
  size_t off = 0;
  auto alloc = [&](size_t bytes) -> char* {
    char* p = ws + off;
    off += (bytes + 255) & ~(size_t)255;
    return p;
  };
  bf16*  Wiou = (bf16*)alloc((size_t)768 * 512 * 2);
  bf16*  Wf   = (bf16*)alloc((size_t)256 * 512 * 2);
  float* biou = (float*)alloc(768 * 4);
  float* bfc  = (float*)alloc(256 * 4);
  bf16*  Xb   = (bf16*)alloc((size_t)131071 * 256 * 2);  // 67.1 MB
  bf16*  H    = (bf16*)alloc((size_t)65536 * 256 * 2);   // 33.6 MB (level-local)
  bf16*  HsA  = (bf16*)alloc((size_t)32768 * 256 * 2);   // 16.8 MB
  bf16*  HsB  = (bf16*)alloc((size_t)32768 * 256 * 2);   // 16.8 MB
  bf16*  FCb  = (bf16*)alloc((size_t)32768 * 256 * 2);   // 16.8 MB (levels 15..13)
  bf16*  C    = (bf16*)alloc((size_t)65536 * 256 * 2);   // 33.6 MB (level-local)
  bf16*  H2   = (bf16*)alloc((size_t)4096 * 256 * 2);    // 2.1 MB (fused ping-pong)
  bf16*  C2   = (bf16*)alloc((size_t)4096 * 256 * 2);    // 2.1 MB

  prep_weights<<<2048, 256, 0, stream>>>(Wioux, Wiouh, Wfx, Wfh,
                                         bioux, biouh, bfx, bfh,
                                         Wiou, Wf, biou, bfc);
  convert_x<<<32768, 256, 0, stream>>>(X, Xb);

  // Leaf level: K=256 (x only); writes C/H rows [0,65536), HsA [0,32768)
  iou_gemm<<<8 * 512, 256, 0, stream>>>(
      Xb, LEAF_START, HsA /*unused*/, nullptr, biou, Wiou,
      C, H, HsA, out, LEAF_COUNT, 256, 0);

  // Large internal levels 15..13 (two dispatches each; 1-D swizzled grids).
  for (int lvl = 15; lvl > FUSE_TOP; --lvl) {
    const int count = 1 << lvl;
    const int s = count - 1;
    const int M2 = 2 * count;
    const bf16* Hsin = (lvl & 1) ? HsA : HsB;
    bf16* Hsout      = (lvl & 1) ? HsB : HsA;
    f_gemm<<<2 * (M2 / 128), 256, 0, stream>>>(
        Xb, s, H, C, bfc, Wf, FCb, M2);
    iou_gemm<<<8 * (count / 128), 256, 0, stream>>>(
        Xb, s, Hsin, FCb, biou, Wiou, C, H, Hsout, out, count, 512, 0);
  }

  // Fused levels 12..0: one dispatch per level; H/C ping-pong between the
  // big level-local buffers and the small H2/C2 pair.
  for (int lvl = FUSE_TOP; lvl >= 0; --lvl) {
    const int count = 1 << lvl;
    const int s = count - 1;
    const bf16* Hsin = (lvl & 1) ? HsA : HsB;
    bf16* Hsout      = (lvl & 1) ? HsB : HsA;
    const int pp = (FUSE_TOP - lvl) & 1;     // 0: in=H,C out=H2,C2 ; 1: reverse
    const bf16* Hin = pp ? H2 : H;
    const bf16* Cin = pp ? C2 : C;
    bf16* Hout      = pp ? H  : H2;
    bf16* Cout      = pp ? C  : C2;
    fused_level<<<dim3(8, (count + 127) / 128), 256, 0, stream>>>(
        Xb, s, Hin, Cin, Hsin, biou, bfc, Wiou, Wf,
        Hout, Cout, Hsout, out, count, lvl == 0);
  }
}

// Round 6
// 652.701 us; speedup vs baseline: 1.7544x; 1.0708x over previous
//
#include <hip/hip_runtime.h>
#include <hip/hip_bf16.h>
#include <cstdint>
#include <cstddef>

// ---------------------------------------------------------------------------
// ChildSumTreeLSTM, complete binary tree N=131071=2^17-1, dim 256.
// Round 10: r9 structure + epilogue transcendental merge + FUSE_TOP=13 +
// XCD swizzle on fused_level.
//  (1) sig(i)tanh(u) = (b-1)/((1+a)(1+b)), a=e^-i, b=e^2u -> 2 exp + 1 rcp
//      (v_rcp via __builtin_amdgcn_rcpf) instead of 2 exp + 2 full f32
//      divides (div_scale/fmas/fixup, ~7 VALU each, no fast-math). Same for
//      h and the f-gate pair. r3 PMC: VALUBusy 54% >> MfmaUtil 12.5% -- gate
//      math on the VALU/TRANS pipes is the dominant non-GEMM cost.
//  (2) FUSE_TOP 13: fused kernel covers 13..0 (-2 dispatches, -FCb traffic).
//  (3) fused_level: 1-D grid + bijective XCD chunk swizzle (same as iou_gemm).
// Leaf + levels 15..14 keep the two-kernel path with XCD chunk swizzle.
//   fused LDS: 32+4+16+12+16 = 80 KB static; acc 80 VGPR (F 32 + IOU 48)
// ---------------------------------------------------------------------------

typedef __bf16 bf16;
typedef bf16 bf16x8 __attribute__((ext_vector_type(8)));
typedef float f32x4 __attribute__((ext_vector_type(4)));

#define LEAF_START 65535
#define LEAF_COUNT 65536
#define FUSE_TOP   13     // levels FUSE_TOP..0 use the fused one-dispatch-per-level kernel

// async global->LDS, 16 B per lane, dest = base + lane*16
#define GLD16(g, l) __builtin_amdgcn_global_load_lds(                         \
    (const __attribute__((address_space(1))) void*)(g),                       \
    (__attribute__((address_space(3))) void*)(l), 16, 0, 0)

// c = sig(i)*tanh(u) + fc ; h = sig(o)*tanh(c).  Merged form: 6 trans
// (4 v_exp + 2 v_rcp) + ~8 VALU, vs 4 exp + 4 full f32 divisions.
__device__ __forceinline__ void gate_ch(float iv, float ov, float uv, float fc,
                                        float& cv, float& h1)
{
  const float a  = __expf(-iv);
  const float b  = __expf(2.0f * uv);
  cv = (b - 1.0f) * __builtin_amdgcn_rcpf((1.0f + a) * (1.0f + b)) + fc;
  const float d  = __expf(-ov);
  const float e2 = __expf(2.0f * cv);
  h1 = (e2 - 1.0f) * __builtin_amdgcn_rcpf((1.0f + d) * (1.0f + e2));
}

// FC = sig(s0)*c0 + sig(s1)*c1 = (c0*(1+a1) + c1*(1+a0)) / ((1+a0)(1+a1))
__device__ __forceinline__ float gate_fc(float s0, float s1, float c0, float c1)
{
  const float a0 = __expf(-s0);
  const float a1 = __expf(-s1);
  return (c0 * (1.0f + a1) + c1 * (1.0f + a0)) *
         __builtin_amdgcn_rcpf((1.0f + a0) * (1.0f + a1));
}

__global__ void prep_weights(const float* __restrict__ Wioux, const float* __restrict__ Wiouh,
                             const float* __restrict__ Wfx, const float* __restrict__ Wfh,
                             const float* __restrict__ bioux, const float* __restrict__ biouh,
                             const float* __restrict__ bfx, const float* __restrict__ bfh,
                             bf16* __restrict__ Wiou, bf16* __restrict__ Wf,
                             float* __restrict__ biou, float* __restrict__ bfc)
{
  const int el = blockIdx.x * 256 + threadIdx.x;   // 0 .. 524287
  if (el < 768 * 512) {
    const int r = el >> 9, c = el & 511;
    const float v = (c < 256) ? Wioux[r * 256 + c] : Wiouh[r * 256 + c - 256];
    Wiou[el] = (bf16)v;
  } else {
    const int e2 = el - 768 * 512;
    const int r = e2 >> 9, c = e2 & 511;
    const float v = (c < 256) ? Wfx[r * 256 + c] : Wfh[r * 256 + c - 256];
    Wf[e2] = (bf16)v;
  }
  if (el < 768)       biou[el] = bioux[el] + biouh[el];
  else if (el < 1024) bfc[el - 768] = bfx[el - 768] + bfh[el - 768];
}

__global__ void convert_x(const float* __restrict__ X, bf16* __restrict__ Xb)
{
  const int i = blockIdx.x * 256 + threadIdx.x;    // float4 index
  if (i < (131071 * 256) / 4) {
    const float4 v = ((const float4*)X)[i];
    union { ushort4 u; bf16 b[4]; } cv;
    cv.b[0] = (bf16)v.x; cv.b[1] = (bf16)v.y; cv.b[2] = (bf16)v.z; cv.b[3] = (bf16)v.w;
    ((ushort4*)Xb)[i] = cv.u;
  }
}

// IOU tile: A[M x K] = [ Xb[xbase+row] | Hsin[row] ], B = Wiou (768 x 512).
// Tile: 128 rows x 32 channels (96 cols: part*32+ch). Each wave: 64 rows
// (waveM) x 16 channels (waveN) x 3 parts -> lane-local i,o,u.
// Epilogue: c = sig(i)tanh(u) + FC; h = sig(o)tanh(c); emit C, H, Hsum.
__device__ __forceinline__ void iou_tile(
    bf16* __restrict__ As /*128*64*/, bf16* __restrict__ Bs /*96*64*/,
    const bf16* __restrict__ Xb, int xbase,
    const bf16* __restrict__ Hsin, const bf16* __restrict__ FCb,
    const float* __restrict__ biou, const bf16* __restrict__ Wiou,
    bf16* __restrict__ Cst, bf16* __restrict__ H, bf16* __restrict__ Hsout,
    float* __restrict__ out, int M, int K, int isRoot, int bx, int by)
{
  const int t = threadIdx.x;
  const int wave = t >> 6, lane = t & 63;
  const int quad = lane >> 4, lc = lane & 15;
  const int waveM = wave >> 1, waveN = wave & 1;
  const int mBase = by * 128;
  const int chBase = bx * 32;
  const int lrow = lane >> 3;                      // 0..7
  const int lcol8 = ((lane & 7) ^ lrow) << 3;      // swizzled 8-elem block
  const int Mm1 = M - 1;
  f32x4 acc[4][3] = {};

  auto ktile = [&](const bf16* __restrict__ abase, int ka, int kb) {
#pragma unroll
    for (int ii = 0; ii < 4; ++ii) {
      const int idx = wave * 4 + ii;
      const int r = idx * 8 + lrow;
      int g = mBase + r; g = g > Mm1 ? Mm1 : g;
      GLD16(abase + (size_t)g * 256 + ka + lcol8, &As[idx * 512]);
    }
#pragma unroll
    for (int ii = 0; ii < 3; ++ii) {
      const int idx = wave * 3 + ii;
      const int rb = idx * 8 + lrow;               // 0..95
      const int grow = (rb >> 5) * 256 + chBase + (rb & 31);
      GLD16(Wiou + (size_t)grow * 512 + kb + lcol8, &Bs[idx * 512]);
    }
    __syncthreads();
#pragma unroll
    for (int kk = 0; kk < 64; kk += 32) {
      const int lb = (kk >> 3) + quad;
      bf16x8 a[4];
#pragma unroll
      for (int mf = 0; mf < 4; ++mf) {
        const int rA = waveM * 64 + mf * 16 + lc;
        a[mf] = *(const bf16x8*)&As[rA * 64 + ((lb ^ (rA & 7)) << 3)];
      }
#pragma unroll
      for (int p = 0; p < 3; ++p) {
        const int rB = p * 32 + waveN * 16 + lc;
        bf16x8 b = *(const bf16x8*)&Bs[rB * 64 + ((lb ^ (rB & 7)) << 3)];
#pragma unroll
        for (int mf = 0; mf < 4; ++mf)
          acc[mf][p] = __builtin_amdgcn_mfma_f32_16x16x32_bf16(a[mf], b, acc[mf][p], 0, 0, 0);
      }
    }
    __syncthreads();
  };

#pragma unroll
  for (int kt = 0; kt < 256; kt += 64) ktile(Xb + (size_t)xbase * 256, kt, kt);
  if (K == 512) {
#pragma unroll
    for (int kt = 0; kt < 256; kt += 64) ktile(Hsin, kt, kt + 256);
  }

  const int ch = chBase + waveN * 16 + lc;
  const float bi = biou[ch], bo = biou[256 + ch], bu = biou[512 + ch];
#pragma unroll
  for (int mf = 0; mf < 4; ++mf) {
    const int row0 = mBase + waveM * 64 + mf * 16 + quad * 4;
    float hv[4] = {0.f, 0.f, 0.f, 0.f};
#pragma unroll
    for (int r = 0; r < 4; ++r) {
      const int rw = row0 + r;
      if (rw < M) {
        const float fc = FCb ? (float)FCb[(size_t)rw * 256 + ch] : 0.0f;
        float cv, h1;
        gate_ch(acc[mf][0][r] + bi, acc[mf][1][r] + bo, acc[mf][2][r] + bu, fc, cv, h1);
        hv[r] = h1;
        Cst[(size_t)rw * 256 + ch] = (bf16)cv;
        H[(size_t)rw * 256 + ch] = (bf16)h1;
        if (isRoot && rw == 0) { out[ch] = cv; out[256 + ch] = h1; }
      }
    }
    if (row0 + 1 < M) Hsout[(size_t)(row0 >> 1) * 256 + ch] = (bf16)(hv[0] + hv[1]);
    if (row0 + 3 < M) Hsout[(size_t)((row0 >> 1) + 1) * 256 + ch] = (bf16)(hv[2] + hv[3]);
  }
}

// F tile over children: A[j] = [ Xb[parent(j)] | H[j] ], B = Wf (256 x 512).
// m97 profile: 128 x 128 tile, waves 2x2, acc 64. Used for levels 15..14.
__device__ __forceinline__ void f_tile(
    bf16* __restrict__ As /*128*64*/, bf16* __restrict__ Bs /*128*64*/,
    const bf16* __restrict__ Xb, int xbase,
    const bf16* __restrict__ H, const bf16* __restrict__ Cc,
    const float* __restrict__ bfc, const bf16* __restrict__ Wf,
    bf16* __restrict__ FCb, int M2, int bx, int by)
{
  const int t = threadIdx.x;
  const int wave = t >> 6, lane = t & 63;
  const int quad = lane >> 4, lc = lane & 15;
  const int waveM = wave >> 1, waveN = wave & 1;
  const int mBase = by * 128;
  const int nBase = bx * 128;
  const int lrow = lane >> 3;
  const int lcol8 = ((lane & 7) ^ lrow) << 3;
  const int Mm1 = M2 - 1;
  f32x4 acc[4][4] = {};

  auto ktile = [&](bool xphase, int ka, int kb) {
#pragma unroll
    for (int ii = 0; ii < 4; ++ii) {
      const int idx = wave * 4 + ii;
      const int r = idx * 8 + lrow;
      int j = mBase + r; j = j > Mm1 ? Mm1 : j;
      const bf16* src = xphase ? Xb + (size_t)(xbase + (j >> 1)) * 256 + ka + lcol8
                               : H + (size_t)j * 256 + ka + lcol8;
      GLD16(src, &As[idx * 512]);
    }
#pragma unroll
    for (int ii = 0; ii < 4; ++ii) {
      const int idx = wave * 4 + ii;
      const int rb = idx * 8 + lrow;
      GLD16(Wf + (size_t)(nBase + rb) * 512 + kb + lcol8, &Bs[idx * 512]);
    }
    __syncthreads();
#pragma unroll
    for (int kk = 0; kk < 64; kk += 32) {
      const int lb = (kk >> 3) + quad;
      bf16x8 a[4];
#pragma unroll
      for (int mf = 0; mf < 4; ++mf) {
        const int rA = waveM * 64 + mf * 16 + lc;
        a[mf] = *(const bf16x8*)&As[rA * 64 + ((lb ^ (rA & 7)) << 3)];
      }
#pragma unroll
      for (int nf = 0; nf < 4; ++nf) {
        const int rB = waveN * 64 + nf * 16 + lc;
        bf16x8 b = *(const bf16x8*)&Bs[rB * 64 + ((lb ^ (rB & 7)) << 3)];
#pragma unroll
        for (int mf = 0; mf < 4; ++mf)
          acc[mf][nf] = __builtin_amdgcn_mfma_f32_16x16x32_bf16(a[mf], b, acc[mf][nf], 0, 0, 0);
      }
    }
    __syncthreads();
  };

#pragma unroll
  for (int kt = 0; kt < 256; kt += 64) ktile(true, kt, kt);
#pragma unroll
  for (int kt = 0; kt < 256; kt += 64) ktile(false, kt, kt + 256);

#pragma unroll
  for (int nf = 0; nf < 4; ++nf) {
    const int col = nBase + waveN * 64 + nf * 16 + lc;
    const float bv = bfc[col];
#pragma unroll
    for (int mf = 0; mf < 4; ++mf) {
      const int j0 = mBase + waveM * 64 + mf * 16 + quad * 4;
#pragma unroll
      for (int p = 0; p < 4; p += 2) {
        const int j = j0 + p;
        if (j < M2) {
          const float c0 = (float)Cc[(size_t)j * 256 + col];
          const float c1 = (float)Cc[(size_t)(j + 1) * 256 + col];
          FCb[(size_t)(j >> 1) * 256 + col] =
              (bf16)gate_fc(acc[mf][nf][p] + bv, acc[mf][nf][p + 1] + bv, c0, c1);
        }
      }
    }
  }
}

// Standalone wrappers for the large levels. 1-D grid + XCD chunk swizzle (r8).
__global__ __launch_bounds__(256) void iou_gemm(
    const bf16* __restrict__ Xb, int xbase,
    const bf16* __restrict__ Hsin, const bf16* __restrict__ FCb,
    const float* __restrict__ biou, const bf16* __restrict__ Wiou,
    bf16* __restrict__ Cst, bf16* __restrict__ H, bf16* __restrict__ Hsout,
    float* __restrict__ out, int M, int K, int isRoot)
{
  __shared__ bf16 As[128 * 64];   // 16 KB
  __shared__ bf16 Bs[96 * 64];    // 12 KB
  const int chunk = gridDim.x >> 3;                    // grid multiple of 8
  const int tile = (blockIdx.x & 7) * chunk + (blockIdx.x >> 3);
  iou_tile(As, Bs, Xb, xbase, Hsin, FCb, biou, Wiou, Cst, H, Hsout,
           out, M, K, isRoot, tile & 7, tile >> 3);
}

__global__ __launch_bounds__(256) void f_gemm(
    const bf16* __restrict__ Xb, int xbase,
    const bf16* __restrict__ H, const bf16* __restrict__ Cc,
    const float* __restrict__ bfc, const bf16* __restrict__ Wf,
    bf16* __restrict__ FCb, int M2)
{
  __shared__ bf16 As[128 * 64];
  __shared__ bf16 Bs[128 * 64];
  const int chunk = gridDim.x >> 3;                    // grid multiple of 8
  const int tile = (blockIdx.x & 7) * chunk + (blockIdx.x >> 3);
  f_tile(As, Bs, Xb, xbase, H, Cc, bfc, Wf, FCb, M2, tile & 1, tile >> 1);
}

// Fused per-level kernel (levels FUSE_TOP..0), INTERLEAVED F+IOU (r9).
// 1-D grid with XCD chunk swizzle (bx fastest within a chunk).
__global__ __launch_bounds__(256) void fused_level(
    const bf16* __restrict__ Xb, int xbase,
    const bf16* __restrict__ Hin, const bf16* __restrict__ Cin,
    const bf16* __restrict__ Hsin,
    const float* __restrict__ biou, const float* __restrict__ bfc,
    const bf16* __restrict__ Wiou, const bf16* __restrict__ Wf,
    bf16* __restrict__ Hout, bf16* __restrict__ Cout, bf16* __restrict__ Hsout,
    float* __restrict__ out, int count, int isRoot)
{
  __shared__ bf16 As_f[256 * 64];   // 32 KB
  __shared__ bf16 Bs_f[32 * 64];    //  4 KB
  __shared__ bf16 As_i[128 * 64];   // 16 KB
  __shared__ bf16 Bs_i[96 * 64];    // 12 KB
  __shared__ float FCs[128 * 32];   // 16 KB   total 80 KB

  const int t = threadIdx.x;
  const int wave = t >> 6, lane = t & 63;
  const int quad = lane >> 4, lc = lane & 15;
  const int waveM = wave >> 1, waveN = wave & 1;
  const int chunk = gridDim.x >> 3;                    // grid multiple of 8
  const int tile = (blockIdx.x & 7) * chunk + (blockIdx.x >> 3);
  const int bx = tile & 7, by = tile >> 3;
  const int mBase = by * 128;
  const int chBase = bx * 32;
  const int lrow = lane >> 3;
  const int lcol8 = ((lane & 7) ^ lrow) << 3;

  const int M = count, Mm1 = M - 1;
  const int M2 = count * 2, M2m1 = M2 - 1;

  f32x4 accf[4][2] = {};   // F: 64 child rows/wave x 32 cols
  f32x4 acci[4][3] = {};   // IOU: 64 rows (waveM) x 16 ch (waveN) x 3 parts

  // 8 combined stages; stage kt covers K-slice [kt*64, kt*64+64) of 512.
  // kt<4: x-part (A from Xb); kt>=4: h-part (A from Hin / Hsin).
#pragma unroll
  for (int kt = 0; kt < 8; ++kt) {
    const bool xph = kt < 4;
    const int ka = (kt & 3) * 64;        // source-row K offset
    const int kb = kt * 64;              // weight-row K offset (0..448)
    // F A: 32 issues (8/wave), 256 child rows
#pragma unroll
    for (int ii = 0; ii < 8; ++ii) {
      const int idx = wave * 8 + ii;
      const int rl = idx * 8 + lrow;
      int j = 2 * mBase + rl; j = j > M2m1 ? M2m1 : j;
      const bf16* src = xph ? Xb + (size_t)(xbase + (j >> 1)) * 256 + ka + lcol8
                            : Hin + (size_t)j * 256 + ka + lcol8;
      GLD16(src, &As_f[idx * 512]);
    }
    // F B: 4 issues (1/wave), 32 Wf rows
    {
      const int rb = wave * 8 + lrow;
      GLD16(Wf + (size_t)(chBase + rb) * 512 + kb + lcol8, &Bs_f[wave * 512]);
    }
    // IOU A: 16 issues (4/wave), 128 node rows
#pragma unroll
    for (int ii = 0; ii < 4; ++ii) {
      const int idx = wave * 4 + ii;
      const int r = idx * 8 + lrow;
      int g = mBase + r; g = g > Mm1 ? Mm1 : g;
      const bf16* src = xph ? Xb + (size_t)(xbase + g) * 256 + ka + lcol8
                            : Hsin + (size_t)g * 256 + ka + lcol8;
      GLD16(src, &As_i[idx * 512]);
    }
    // IOU B: 12 issues (3/wave), 96 Wiou rows (3 parts x 32 ch)
#pragma unroll
    for (int ii = 0; ii < 3; ++ii) {
      const int idx = wave * 3 + ii;
      const int rb = idx * 8 + lrow;               // 0..95
      const int grow = (rb >> 5) * 256 + chBase + (rb & 31);
      GLD16(Wiou + (size_t)grow * 512 + kb + lcol8, &Bs_i[idx * 512]);
    }
    __syncthreads();
#pragma unroll
    for (int kk = 0; kk < 64; kk += 32) {
      const int lb = (kk >> 3) + quad;
      // F MFMAs (16 per stage-half)
      bf16x8 af[4];
#pragma unroll
      for (int mf = 0; mf < 4; ++mf) {
        const int rA = wave * 64 + mf * 16 + lc;
        af[mf] = *(const bf16x8*)&As_f[rA * 64 + ((lb ^ (rA & 7)) << 3)];
      }
#pragma unroll
      for (int nf = 0; nf < 2; ++nf) {
        const int rB = nf * 16 + lc;
        bf16x8 b = *(const bf16x8*)&Bs_f[rB * 64 + ((lb ^ (rB & 7)) << 3)];
#pragma unroll
        for (int mf = 0; mf < 4; ++mf)
          accf[mf][nf] = __builtin_amdgcn_mfma_f32_16x16x32_bf16(af[mf], b, accf[mf][nf], 0, 0, 0);
      }
      // IOU MFMAs (24 per stage-half)
      bf16x8 ai[4];
#pragma unroll
      for (int mf = 0; mf < 4; ++mf) {
        const int rA = waveM * 64 + mf * 16 + lc;
        ai[mf] = *(const bf16x8*)&As_i[rA * 64 + ((lb ^ (rA & 7)) << 3)];
      }
#pragma unroll
      for (int p = 0; p < 3; ++p) {
        const int rB = p * 32 + waveN * 16 + lc;
        bf16x8 b = *(const bf16x8*)&Bs_i[rB * 64 + ((lb ^ (rB & 7)) << 3)];
#pragma unroll
        for (int mf = 0; mf < 4; ++mf)
          acci[mf][p] = __builtin_amdgcn_mfma_f32_16x16x32_bf16(ai[mf], b, acci[mf][p], 0, 0, 0);
      }
    }
    __syncthreads();
  }

  // F epilogue: FC pairs -> LDS (f32, rows rl>>1 in [0,128), cols 0..31)
#pragma unroll
  for (int nf = 0; nf < 2; ++nf) {
    const int ci = nf * 16 + lc;
    const float bv = bfc[chBase + ci];
#pragma unroll
    for (int mf = 0; mf < 4; ++mf) {
      const int rl0 = wave * 64 + mf * 16 + quad * 4;
#pragma unroll
      for (int p = 0; p < 4; p += 2) {
        const int rl = rl0 + p;                    // even
        const int j = 2 * mBase + rl;
        if (j + 1 < M2) {
          const float c0 = (float)Cin[(size_t)j * 256 + chBase + ci];
          const float c1 = (float)Cin[(size_t)(j + 1) * 256 + chBase + ci];
          FCs[(rl >> 1) * 32 + ci] =
              gate_fc(accf[mf][nf][p] + bv, accf[mf][nf][p + 1] + bv, c0, c1);
        }
      }
    }
  }
  __syncthreads();   // FCs visible to all waves

  // IOU epilogue (FC from LDS)
  const int ch = chBase + waveN * 16 + lc;
  const float bi = biou[ch], bo = biou[256 + ch], bu = biou[512 + ch];
#pragma unroll
  for (int mf = 0; mf < 4; ++mf) {
    const int row0 = mBase + waveM * 64 + mf * 16 + quad * 4;
    float hv[4] = {0.f, 0.f, 0.f, 0.f};
#pragma unroll
    for (int r = 0; r < 4; ++r) {
      const int rw = row0 + r;
      if (rw < M) {
        const float fc = FCs[(rw - mBase) * 32 + (ch - chBase)];
        float cv, h1;
        gate_ch(acci[mf][0][r] + bi, acci[mf][1][r] + bo, acci[mf][2][r] + bu, fc, cv, h1);
        hv[r] = h1;
        Cout[(size_t)rw * 256 + ch] = (bf16)cv;
        Hout[(size_t)rw * 256 + ch] = (bf16)h1;
        if (isRoot && rw == 0) { out[ch] = cv; out[256 + ch] = h1; }
      }
    }
    if (row0 + 1 < M) Hsout[(size_t)(row0 >> 1) * 256 + ch] = (bf16)(hv[0] + hv[1]);
    if (row0 + 3 < M) Hsout[(size_t)((row0 >> 1) + 1) * 256 + ch] = (bf16)(hv[2] + hv[3]);
  }
}

extern "C" void kernel_launch(void* const* d_in, const int* in_sizes, int n_in,
                              void* d_out, int out_size, void* d_ws, size_t ws_size,
                              hipStream_t stream)
{
  const float* X      = (const float*)d_in[0];
  const float* Wioux  = (const float*)d_in[1];
  const float* bioux  = (const float*)d_in[2];
  const float* Wiouh  = (const float*)d_in[3];
  const float* biouh  = (const float*)d_in[4];
  const float* Wfx    = (const float*)d_in[5];
  const float* bfx    = (const float*)d_in[6];
  const float* Wfh    = (const float*)d_in[7];
  const float* bfh    = (const float*)d_in[8];
  float* out = (float*)d_out;
  (void)in_sizes; (void)n_in; (void)out_size; (void)ws_size;

  // workspace: ~197 MB
  char* ws = (char*)d_ws;
  size_t off = 0;
  auto alloc = [&](size_t bytes) -> char* {
    char* p = ws + off;
    off += (bytes + 255) & ~(size_t)255;
    return p;
  };
  bf16*  Wiou = (bf16*)alloc((size_t)768 * 512 * 2);
  bf16*  Wf   = (bf16*)alloc((size_t)256 * 512 * 2);
  float* biou = (float*)alloc(768 * 4);
  float* bfc  = (float*)alloc(256 * 4);
  bf16*  Xb   = (bf16*)alloc((size_t)131071 * 256 * 2);  // 67.1 MB
  bf16*  H    = (bf16*)alloc((size_t)65536 * 256 * 2);   // 33.6 MB (level-local)
  bf16*  HsA  = (bf16*)alloc((size_t)32768 * 256 * 2);   // 16.8 MB
  bf16*  HsB  = (bf16*)alloc((size_t)32768 * 256 * 2);   // 16.8 MB
  bf16*  FCb  = (bf16*)alloc((size_t)32768 * 256 * 2);   // 16.8 MB (levels 15..14)
  bf16*  C    = (bf16*)alloc((size_t)65536 * 256 * 2);   // 33.6 MB (level-local)
  bf16*  H2   = (bf16*)alloc((size_t)8192 * 256 * 2);    // 4.2 MB (fused ping-pong)
  bf16*  C2   = (bf16*)alloc((size_t)8192 * 256 * 2);    // 4.2 MB

  prep_weights<<<2048, 256, 0, stream>>>(Wioux, Wiouh, Wfx, Wfh,
                                         bioux, biouh, bfx, bfh,
                                         Wiou, Wf, biou, bfc);
  convert_x<<<32768, 256, 0, stream>>>(X, Xb);

  // Leaf level: K=256 (x only); writes C/H rows [0,65536), HsA [0,32768)
  iou_gemm<<<8 * 512, 256, 0, stream>>>(
      Xb, LEAF_START, HsA /*unused*/, nullptr, biou, Wiou,
      C, H, HsA, out, LEAF_COUNT, 256, 0);

  // Large internal levels 15..14 (two dispatches each; 1-D swizzled grids).
  for (int lvl = 15; lvl > FUSE_TOP; --lvl) {
    const int count = 1 << lvl;
    const int s = count - 1;
    const int M2 = 2 * count;
    const bf16* Hsin = (lvl & 1) ? HsA : HsB;
    bf16* Hsout      = (lvl & 1) ? HsB : HsA;
    f_gemm<<<2 * (M2 / 128), 256, 0, stream>>>(
        Xb, s, H, C, bfc, Wf, FCb, M2);
    iou_gemm<<<8 * (count / 128), 256, 0, stream>>>(
        Xb, s, Hsin, FCb, biou, Wiou, C, H, Hsout, out, count, 512, 0);
  }

  // Fused levels 13..0: one dispatch per level; H/C ping-pong between the
  // big level-local buffers and the small H2/C2 pair.
  for (int lvl = FUSE_TOP; lvl >= 0; --lvl) {
    const int count = 1 << lvl;
    const int s = count - 1;
    const bf16* Hsin = (lvl & 1) ? HsA : HsB;
    bf16* Hsout      = (lvl & 1) ? HsB : HsA;
    const int pp = (FUSE_TOP - lvl) & 1;     // 0: in=H,C out=H2,C2 ; 1: reverse
    const bf16* Hin = pp ? H2 : H;
    const bf16* Cin = pp ? C2 : C;
    bf16* Hout      = pp ? H  : H2;
    bf16* Cout      = pp ? C  : C2;
    fused_level<<<8 * ((count + 127) / 128), 256, 0, stream>>>(
        Xb, s, Hin, Cin, Hsin, biou, bfc, Wiou, Wf,
        Hout, Cout, Hsout, out, count, lvl == 0);
  }
}